// Round 13
// baseline (652.602 us; speedup 1.0000x reference)
//
#include <hip/hip_runtime.h>
#include <cmath>

#define BC 2048          // B*W sequences
#define S_LEN 8192
#define MODES 42
// padded pyramid: L1@0(4101) L2@4104(2056) L3@6160(1033) L4@7196(522)
//                 L5@7720(266) L6@7988(138) L7@8128(74) L8@8204(42)
#define HTOT 8248
#define LO_STR 1036      // padded stride for the 1033-long lo buffers
#define L1_STR 4104      // padded stride for the 4101-long lo1 buffer

static constexpr float C_LO[12] = {
  0.11154074335008017f, 0.4946238903983854f, 0.7511339080215775f,
  0.3152503517092432f, -0.22626469396516913f, -0.12976686756709563f,
  0.09750160558707936f, 0.02752286553001629f, -0.031582039318031156f,
  0.0005538422009938016f, 0.004777257511010651f, -0.00107730108499558f };

__device__ __forceinline__ float rec_lo_c(int k){ return C_LO[k]; }
__device__ __forceinline__ float rec_hi_c(int k){ float v = C_LO[11-k]; return (k&1)? -v : v; }
__device__ __forceinline__ float dec_lo_c(int k){ return C_LO[11-k]; }
__device__ __forceinline__ float dec_hi_c(int k){ float v = C_LO[k];    return (k&1)?  v : -v; }

// branchless erf (Abramowitz-Stegun 7.1.26, |err|<=1.5e-7)
__device__ __forceinline__ float erf_fast(float x){
  float ax = fabsf(x);
  float t  = __fdividef(1.0f, 1.0f + 0.3275911f * ax);
  float p  = ((((1.061405429f * t - 1.453152027f) * t) + 1.421413741f) * t - 0.284496736f) * t + 0.254829592f;
  float y  = 1.0f - p * t * __expf(-ax * ax);
  return copysignf(y, x);
}
__device__ __forceinline__ float gelu_f(float x){
  return 0.5f * x * (1.0f + erf_fast(x * 0.70710678118654752440f));
}

__device__ __forceinline__ int reflect_i(int t, int n){
  t = (t < 0) ? (-1 - t) : t;
  t = (t >= n) ? (2 * n - 1 - t) : t;
  return t;
}

__device__ __forceinline__ unsigned short bf16_rn(float x){
  unsigned int b = __float_as_uint(x);
  b += 0x7FFF + ((b >> 16) & 1);
  return (unsigned short)(b >> 16);
}
__device__ __forceinline__ float bf16_to_f(unsigned short h){
  return __uint_as_float(((unsigned int)h) << 16);
}

typedef short  v8s __attribute__((ext_vector_type(8)));
typedef float  v4f __attribute__((ext_vector_type(4)));
typedef unsigned short u16;

__device__ __forceinline__ void ld3f4(float* w, const float* s){
  *(float4*)&w[0] = *(const float4*)&s[0];
  *(float4*)&w[4] = *(const float4*)&s[4];
  *(float4*)&w[8] = *(const float4*)&s[8];
}
__device__ __forceinline__ void ld5f4(float* w, const float* s){
  *(float4*)&w[0]  = *(const float4*)&s[0];
  *(float4*)&w[4]  = *(const float4*)&s[4];
  *(float4*)&w[8]  = *(const float4*)&s[8];
  *(float4*)&w[12] = *(const float4*)&s[12];
  *(float4*)&w[16] = *(const float4*)&s[16];
}
__device__ __forceinline__ void ld4f2(float* w, const float* s){
  *(float2*)&w[0] = *(const float2*)&s[0];
  *(float2*)&w[2] = *(const float2*)&s[2];
  *(float2*)&w[4] = *(const float2*)&s[4];
  *(float2*)&w[6] = *(const float2*)&s[6];
}

// zero-pad staging: dst[j] = (0<=g0+j<n) ? src[g0+j] : 0 ; g0%4==0, cnt%4==0
__device__ __forceinline__ void stage_g(float* dst, const float* src, int g0, int cnt, int n){
  for (int j4 = threadIdx.x; j4 < (cnt >> 2); j4 += 256) {
    int g = g0 + 4 * j4;
    float4 val;
    if (g >= 0 && g + 3 < n) val = *(const float4*)&src[g];
    else {
      val.x = (g   >= 0 && g   < n) ? src[g]   : 0.f;
      val.y = (g+1 >= 0 && g+1 < n) ? src[g+1] : 0.f;
      val.z = (g+2 >= 0 && g+2 < n) ? src[g+2] : 0.f;
      val.w = (g+3 >= 0 && g+3 < n) ? src[g+3] : 0.f;
    }
    *(float4*)&dst[4*j4] = val;
  }
}

__device__ __forceinline__ void stage_band4(float* dst, const float* src, int len, int alloc){
  for (int i4 = threadIdx.x; i4 < (alloc >> 2); i4 += 256) {
    int i = 4 * i4;
    float4 v;
    if (i + 3 < len) v = *(const float4*)&src[i];
    else {
      v.x = (i   < len) ? src[i]   : 0.f;
      v.y = (i+1 < len) ? src[i+1] : 0.f;
      v.z = (i+2 < len) ? src[i+2] : 0.f;
      v.w = (i+3 < len) ? src[i+3] : 0.f;
    }
    *(float4*)&dst[i] = v;
  }
}

// 4 IDWT outputs m=u0..u0+3 from windows wl/wh[8]; tap base SH + (d>>1)
template<int SH>
__device__ __forceinline__ void idwt4s(const float* wl, const float* wh, float* o4){
  #pragma unroll
  for (int d = 0; d < 4; ++d) {
    const int q = SH + (d >> 1);
    float acc = 0.f;
    if (d & 1) {
      #pragma unroll
      for (int i = 0; i < 6; ++i) acc += wl[q+i]*dec_lo_c(2*i)   + wh[q+i]*dec_hi_c(2*i);
    } else {
      #pragma unroll
      for (int i = 0; i < 6; ++i) acc += wl[q+i]*dec_lo_c(2*i+1) + wh[q+i]*dec_hi_c(2*i+1);
    }
    o4[d] = acc;
  }
}

// ---------------------------------------------------------------- prep: split weights to hi/lo bf16 in swizzled layout
__global__ __launch_bounds__(256) void prep_split(
    const float* __restrict__ fc1w, const float* __restrict__ cw,
    u16* __restrict__ whH, u16* __restrict__ whL,
    u16* __restrict__ wcH, u16* __restrict__ wcL)
{
  int i = blockIdx.x * 256 + threadIdx.x;
  if (i < 8192) {
    int c = i >> 7, j = i & 127;
    float wv = fc1w[i];
    u16 h = bf16_rn(wv);
    float lo = wv - bf16_to_f(h);
    int cs = c ^ ((j & 7) << 3);
    whH[j * 64 + cs] = h; whL[j * 64 + cs] = bf16_rn(lo);
  }
  int k = i - 8192;
  if (k >= 0 && k < 16384) {
    int l = k >> 12, r = k & 4095;
    int c = r >> 6, o = r & 63;
    float wv = cw[k];
    u16 h = bf16_rn(wv);
    float lo = wv - bf16_to_f(h);
    int cs = c ^ ((o & 7) << 3);
    wcH[l * 4096 + o * 64 + cs] = h; wcL[l * 4096 + o * 64 + cs] = bf16_rn(lo);
  }
}

// ---------------------------------------------------------------- fc0
__global__ __launch_bounds__(256) void fc0_kernel(
    const float* __restrict__ x, const float* __restrict__ w,
    const float* __restrict__ bias, float* __restrict__ v)
{
  int p = blockIdx.x * 256 + threadIdx.x;
  int b = p >> 13, s = p & 8191;
  float xv = x[p];
  float g  = (float)s * (1.0f / 8191.0f);
  for (int c = 0; c < 64; ++c) {
    v[((size_t)(b * 64 + c)) * S_LEN + s] = xv * w[c] + g * w[64 + c] + bias[c];
  }
}

// ---------------------------------------------------------------- DWT big: 8192->4101->2056->1033, 4 chunks/seq
__global__ __launch_bounds__(256) void dwt_big(
    const float* __restrict__ vin, float* __restrict__ highs, float* __restrict__ lo_f)
{
  __shared__ alignas(16) float sVE[1096], sVO[1096];
  __shared__ alignas(16) float sL1Eb[548], sL1Ob[548];   // +4 front pad
  __shared__ alignas(16) float sL2E[276], sL2O[276];
  float* sL1E = sL1Eb + 4;
  float* sL1O = sL1Ob + 4;

  int seq = blockIdx.x >> 2, c = blockIdx.x & 3;
  const float* src = vin + (size_t)seq * S_LEN;
  float* hseq = highs + (size_t)seq * HTOT;
  int tid = threadIdx.x;

  int g0 = 2080 * c - 76;
  for (int j4 = tid; j4 < 545; j4 += 256) {
    int g = g0 + 4 * j4;
    float4 val;
    if (g >= 0 && g + 3 < 8192) val = *(const float4*)&src[g];
    else {
      val.x = src[reflect_i(g,   8192)];
      val.y = src[reflect_i(g+1, 8192)];
      val.z = src[reflect_i(g+2, 8192)];
      val.w = src[reflect_i(g+3, 8192)];
    }
    *(float2*)&sVE[2*j4] = make_float2(val.x, val.z);
    *(float2*)&sVO[2*j4] = make_float2(val.y, val.w);
  }
  __syncthreads();

  {
    int base1m = 1040 * c - 32;
    int uh1 = (c < 3) ? 1072 : 1013;
    for (int u0 = 4 * tid; u0 < 1084; u0 += 1024) {
      float we[12], wo[12];
      ld3f4(we, &sVE[u0]); ld3f4(wo, &sVO[u0]);
      float lo4[4], hi4[4];
      #pragma unroll
      for (int d = 0; d < 4; ++d) {
        float alo = 0.f, ahi = 0.f;
        #pragma unroll
        for (int j = 0; j < 6; ++j) {
          float e = we[d+1+j], oo = wo[d+1+j];
          alo += e * rec_lo_c(2*j) + oo * rec_lo_c(2*j+1);
          ahi += e * rec_hi_c(2*j) + oo * rec_hi_c(2*j+1);
        }
        lo4[d] = alo; hi4[d] = ahi;
      }
      *(float2*)&sL1E[u0 >> 1] = make_float2(lo4[0], lo4[2]);
      *(float2*)&sL1O[u0 >> 1] = make_float2(lo4[1], lo4[3]);
      if (u0 >= 32 && u0 + 3 < uh1) {
        *(float4*)&hseq[base1m + u0] = make_float4(hi4[0], hi4[1], hi4[2], hi4[3]);
      } else {
        #pragma unroll
        for (int d = 0; d < 4; ++d) {
          int u = u0 + d;
          if (u >= 32 && u < uh1) hseq[base1m + u] = hi4[d];
        }
      }
    }
  }
  __syncthreads();
  if (c == 0) {
    for (int u = tid; u < 32; u += 256) {
      int j = 63 - u;
      float v = (j & 1) ? sL1O[j >> 1] : sL1E[j >> 1];
      if (u & 1) sL1O[u >> 1] = v; else sL1E[u >> 1] = v;
    }
  }
  if (c == 3) {
    for (int u = 1013 + tid; u < 1084; u += 256) {
      int j = 2025 - u;
      float v = (j & 1) ? sL1O[j >> 1] : sL1E[j >> 1];
      if (u & 1) sL1O[u >> 1] = v; else sL1E[u >> 1] = v;
    }
  }
  __syncthreads();

  {
    int base2m = 520 * c - 12;
    int uh2 = (c < 3) ? 532 : 508;
    for (int u0 = 4 * tid; u0 < 536; u0 += 1024) {
      float we[12], wo[12];
      ld3f4(we, &sL1E[u0 - 4]); ld3f4(wo, &sL1O[u0 - 4]);
      float lo4[4], hi4[4];
      #pragma unroll
      for (int d = 0; d < 4; ++d) {
        float alo = 0.f, ahi = 0.f;
        #pragma unroll
        for (int j = 0; j < 6; ++j) {
          float e = we[d+3+j], oo = wo[d+3+j];
          alo += e * rec_lo_c(2*j) + oo * rec_lo_c(2*j+1);
          ahi += e * rec_hi_c(2*j) + oo * rec_hi_c(2*j+1);
        }
        lo4[d] = alo; hi4[d] = ahi;
      }
      *(float2*)&sL2E[u0 >> 1] = make_float2(lo4[0], lo4[2]);
      *(float2*)&sL2O[u0 >> 1] = make_float2(lo4[1], lo4[3]);
      if (u0 >= 12 && u0 < uh2)
        *(float4*)&hseq[4104 + base2m + u0] = make_float4(hi4[0], hi4[1], hi4[2], hi4[3]);
    }
  }
  __syncthreads();
  if (c == 0) {
    for (int u = tid; u < 12; u += 256) {
      int j = 23 - u;
      float v = (j & 1) ? sL2O[j >> 1] : sL2E[j >> 1];
      if (u & 1) sL2O[u >> 1] = v; else sL2E[u >> 1] = v;
    }
  }
  if (c == 3) {
    for (int u = 508 + tid; u < 536; u += 256) {
      int j = 1015 - u;
      float v = (j & 1) ? sL2O[j >> 1] : sL2E[j >> 1];
      if (u & 1) sL2O[u >> 1] = v; else sL2E[u >> 1] = v;
    }
  }
  __syncthreads();

  for (int u0 = 4 * tid; u0 < 260; u0 += 1024) {
    float we[12], wo[12];
    ld3f4(we, &sL2E[u0]); ld3f4(wo, &sL2O[u0]);
    float lo4[4], hi4[4];
    #pragma unroll
    for (int d = 0; d < 4; ++d) {
      float alo = 0.f, ahi = 0.f;
      #pragma unroll
      for (int j = 0; j < 6; ++j) {
        float e = we[d+1+j], oo = wo[d+1+j];
        alo += e * rec_lo_c(2*j) + oo * rec_lo_c(2*j+1);
        ahi += e * rec_hi_c(2*j) + oo * rec_hi_c(2*j+1);
      }
      lo4[d] = alo; hi4[d] = ahi;
    }
    int m0 = 260 * c + u0;
    if (m0 + 3 < 1033) {
      *(float4*)&lo_f[(size_t)seq * LO_STR + m0] = make_float4(lo4[0], lo4[1], lo4[2], lo4[3]);
      *(float4*)&hseq[6160 + m0] = make_float4(hi4[0], hi4[1], hi4[2], hi4[3]);
    } else {
      #pragma unroll
      for (int d = 0; d < 4; ++d) {
        int m = m0 + d;
        if (m < 1033 && u0 + d < 260) {
          lo_f[(size_t)seq * LO_STR + m] = lo4[d];
          hseq[6160 + m] = hi4[d];
        }
      }
    }
  }
}

// ---------------------------------------------------------------- DWT small: 1033->522->266->138->74->42 per seq
__device__ __forceinline__ void dwt_lvl_v(const float* in, int n, float* out, int outn, float* hg)
{
  for (int u0 = 4*(int)threadIdx.x; u0 < outn; u0 += 1024) {
    bool fast = (u0 >= 8) && (2*u0 + 7 < n) && (u0 + 3 < outn);
    if (fast) {
      float w[20];
      ld5f4(w, &in[2*u0 - 12]);
      #pragma unroll
      for (int d = 0; d < 4; ++d) {
        float alo = 0.f, ahi = 0.f;
        #pragma unroll
        for (int k = 0; k < 12; ++k) {
          float x = w[2*d + 2 + k];
          alo += x * rec_lo_c(k); ahi += x * rec_hi_c(k);
        }
        out[u0+d] = alo; hg[u0+d] = ahi;
      }
    } else {
      for (int d = 0; d < 4; ++d) {
        if (u0 + d < outn) {
          float alo = 0.f, ahi = 0.f;
          #pragma unroll
          for (int k = 0; k < 12; ++k) {
            float x = in[reflect_i(2*(u0+d) + k - 10, n)];
            alo += x * rec_lo_c(k); ahi += x * rec_hi_c(k);
          }
          out[u0+d] = alo; hg[u0+d] = ahi;
        }
      }
    }
  }
  __syncthreads();
}

__global__ __launch_bounds__(256) void dwt_small(
    const float* __restrict__ lo_f, float* __restrict__ highs, float* __restrict__ yl)
{
  __shared__ alignas(16) float A[1040], Bb[528];
  int seq = blockIdx.x;
  const float* src = lo_f + (size_t)seq * LO_STR;
  float* hseq = highs + (size_t)seq * HTOT;
  for (int i = 4*(int)threadIdx.x; i < 1033; i += 1024) {
    if (i + 3 < 1033) *(float4*)&A[i] = *(const float4*)&src[i];
    else { for (int d = 0; d < 4; ++d) if (i + d < 1033) A[i+d] = src[i+d]; }
  }
  __syncthreads();
  dwt_lvl_v(A, 1033, Bb, 522, hseq + 7196);
  dwt_lvl_v(Bb, 522, A, 266, hseq + 7720);
  dwt_lvl_v(A, 266, Bb, 138, hseq + 7988);
  dwt_lvl_v(Bb, 138, A, 74,  hseq + 8128);
  dwt_lvl_v(A, 74,  Bb, 42,  hseq + 8204);
  for (int m = threadIdx.x; m < MODES; m += 256) yl[seq * MODES + m] = Bb[m];
}

// ---------------------------------------------------------------- IDWT small + fused channel mix (serial prologue, round-8-validated)
__device__ __forceinline__ void idwt_lvl4(const float* lo, const float* h, float* out, int outn)
{
  for (int u0 = 4*(int)threadIdx.x; u0 < outn; u0 += 1024) {
    int q = u0 >> 1;
    float wl[8], wh[8];
    ld4f2(wl, &lo[q]); ld4f2(wh, &h[q]);
    float o4[4]; idwt4s<0>(wl, wh, o4);
    if (u0 + 3 < outn) *(float4*)&out[u0] = make_float4(o4[0], o4[1], o4[2], o4[3]);
    else { for (int d = 0; d < 4; ++d) if (u0 + d < outn) out[u0+d] = o4[d]; }
  }
  __syncthreads();
}

__global__ __launch_bounds__(256) void idwt_small(
    const float* __restrict__ yl_raw, const float* __restrict__ highs,
    const float* __restrict__ w1l, const float* __restrict__ w2l,
    float* __restrict__ lo_i)
{
  // bands: yl@0(48) yh@48(48) h74@96(80) h138@176(144) h266@320(272) h522@592(528)
  __shared__ alignas(16) float bands[1120], wa[272], wb[528];
  int seq = blockIdx.x;
  int b = seq >> 6, o = seq & 63;
  const float* hseq = highs + (size_t)seq * HTOT;
  int t = threadIdx.x;

  stage_band4(bands + 96,  hseq + 8128, 74, 80);
  stage_band4(bands + 176, hseq + 7988, 138, 144);
  stage_band4(bands + 320, hseq + 7720, 266, 272);
  stage_band4(bands + 592, hseq + 7196, 522, 528);

  if (t >= 42 && t < 48) { bands[t] = 0.f; bands[48 + t] = 0.f; }
  if (t < 42) {
    const float* yr = yl_raw + (size_t)b * 2688 + t;                 // + i*42
    const float* hh = highs + (size_t)(b * 64) * HTOT + 8204 + t;    // + i*HTOT
    const float* wl = w1l + o * 42 + t;                               // + i*2688
    const float* wh = w2l + o * 42 + t;
    float accl = 0.f, acch = 0.f;
    #pragma unroll 4
    for (int i = 0; i < 64; ++i) {
      accl += yr[i * 42] * wl[i * 2688];
      acch += hh[(size_t)i * HTOT] * wh[i * 2688];
    }
    bands[t] = accl; bands[48 + t] = acch;
  }
  __syncthreads();

  idwt_lvl4(bands + 0,   bands + 48,  wa, 74);
  idwt_lvl4(wa,          bands + 96,  wb, 138);
  idwt_lvl4(wb,          bands + 176, wa, 266);
  idwt_lvl4(wa,          bands + 320, wb, 522);

  for (int u0 = 4 * t; u0 < 1033; u0 += 1024) {
    int q = u0 >> 1;
    float wl[8], wh[8];
    ld4f2(wl, &wb[q]); ld4f2(wh, &bands[592 + q]);
    float o4[4]; idwt4s<0>(wl, wh, o4);
    float* dst = lo_i + (size_t)seq * LO_STR + u0;
    if (u0 + 3 < 1033) *(float4*)&dst[0] = make_float4(o4[0], o4[1], o4[2], o4[3]);
    else { for (int d = 0; d < 4; ++d) if (u0 + d < 1033) dst[d] = o4[d]; }
  }
}

// ---------------------------------------------------------------- IDWT mid: 1033->2056->4101, writes lo1
__global__ __launch_bounds__(256) void idwt_mid(
    const float* __restrict__ lo_i, const float* __restrict__ highs, float* __restrict__ lo1)
{
  __shared__ alignas(16) float sL3[288], sH3[288], sL2[544], sH2[544], sL1[1048];
  int seq = blockIdx.x >> 2, c = blockIdx.x & 3;
  const float* hseq = highs + (size_t)seq * HTOT;
  const float* l3   = lo_i + (size_t)seq * LO_STR;
  int g3 = 256*c - 4, g2 = 512*c - 4;
  int t = threadIdx.x;

  stage_g(sL3, l3,          g3, 288, 1033);
  stage_g(sH3, hseq + 6160, g3, 288, 1033);
  stage_g(sH2, hseq + 4104, g2, 544, 2056);
  __syncthreads();

  // s5: m = (512c-2)+u, u in [0,536)
  for (int u0 = 4 * t; u0 < 536; u0 += 1024) {
    int q = u0 >> 1;
    float wl[8], wh[8];
    ld4f2(wl, &sL3[q + 2]); ld4f2(wh, &sH3[q + 2]);
    float o4[4]; idwt4s<1>(wl, wh, o4);
    #pragma unroll
    for (int d = 0; d < 4; ++d) {
      int m = 512*c - 2 + u0 + d;
      o4[d] = (m >= 0 && m < 2056) ? o4[d] : 0.f;
    }
    *(float2*)&sL2[u0 + 2] = make_float2(o4[0], o4[1]);
    *(float2*)&sL2[u0 + 4] = make_float2(o4[2], o4[3]);
  }
  __syncthreads();

  // s6: m = (1024c-2)+u, u in [0,1040); sL1[U] <-> m = 1024c + U - 4
  for (int u0 = 4 * t; u0 < 1040; u0 += 1024) {
    int q = u0 >> 1;
    float wl[8], wh[8];
    ld4f2(wl, &sL2[q + 2]); ld4f2(wh, &sH2[q + 2]);
    float o4[4]; idwt4s<1>(wl, wh, o4);
    #pragma unroll
    for (int d = 0; d < 4; ++d) {
      int m = 1024*c - 2 + u0 + d;
      o4[d] = (m >= 0 && m < 4101) ? o4[d] : 0.f;
    }
    *(float2*)&sL1[u0 + 2] = make_float2(o4[0], o4[1]);
    *(float2*)&sL1[u0 + 4] = make_float2(o4[2], o4[3]);
  }
  __syncthreads();

  // write owned range [1024c, lim) of lo1 from sL1[U], U = m - 1024c + 4
  {
    int lim = (c == 3) ? 4101 : (1024 * c + 1024);
    for (int m0 = 1024 * c + 4 * t; m0 < lim; m0 += 1024) {
      int u = m0 - 1024 * c + 4;
      if (m0 + 3 < lim) {
        *(float4*)&lo1[(size_t)seq * L1_STR + m0] = *(float4*)&sL1[u];
      } else {
        for (int d = 0; d < 4; ++d)
          if (m0 + d < lim) lo1[(size_t)seq * L1_STR + m0 + d] = sL1[u + d];
      }
    }
  }
}

// ---------------------------------------------------------------- final level: lo1(4101)+h1(4101) -> x1(8192), 4 chunks/seq
// verbatim round-9 idwt_big s7 math, fed from global lo1
__global__ __launch_bounds__(256) void final_lvl(
    const float* __restrict__ lo1, const float* __restrict__ highs, float* __restrict__ x1)
{
  __shared__ alignas(16) float sL1[1048], sH1[1048];
  int seq = blockIdx.x >> 2, c = blockIdx.x & 3;
  int g1 = 1024 * c - 4;
  stage_g(sL1, lo1  + (size_t)seq * L1_STR, g1, 1048, 4101);
  stage_g(sH1, highs + (size_t)seq * HTOT,  g1, 1048, 4101);
  __syncthreads();
  int t = threadIdx.x;
  for (int u0 = 4 * t; u0 < 2048; u0 += 1024) {
    int q = u0 >> 1;
    float wl[8], wh[8];
    ld4f2(wl, &sL1[q + 4]); ld4f2(wh, &sH1[q + 4]);
    float o4[4]; idwt4s<0>(wl, wh, o4);
    *(float4*)&x1[(size_t)seq * S_LEN + 2048*c + u0] = make_float4(o4[0], o4[1], o4[2], o4[3]);
  }
}

// ---------------------------------------------------------------- layer pointwise via MFMA (round-9 validated, reads x1)
__global__ __launch_bounds__(256) void pw_mfma(
    const float* __restrict__ x1, float* v,
    const u16* __restrict__ wcH, const u16* __restrict__ wcL,
    const float* __restrict__ cb, int do_gelu)
{
  __shared__ u16 aH[64][64], aL[64][64];
  __shared__ u16 wH[64][64], wL[64][64];
  __shared__ float cbl[64];
  int b  = blockIdx.x >> 7;
  int s0 = (blockIdx.x & 127) << 6;
  int t  = threadIdx.x;

  {
    const v8s* srcH = (const v8s*)wcH;
    const v8s* srcL = (const v8s*)wcL;
    v8s* dstH = (v8s*)&wH[0][0];
    v8s* dstL = (v8s*)&wL[0][0];
    #pragma unroll
    for (int r = 0; r < 2; ++r) {
      dstH[t + 256 * r] = srcH[t + 256 * r];
      dstL[t + 256 * r] = srcL[t + 256 * r];
    }
  }
  if (t < 64) cbl[t] = cb[t];

  #pragma unroll
  for (int r = 0; r < 4; ++r) {
    int idx = t + 256 * r;
    int ch = idx >> 4, p4 = (idx & 15) << 2;
    float4 xv = *(const float4*)&v[((size_t)(b * 64 + ch)) * S_LEN + s0 + p4];
    u16 h0 = bf16_rn(xv.x); aH[p4+0][ch ^ (((p4+0)&7)<<3)] = h0; aL[p4+0][ch ^ (((p4+0)&7)<<3)] = bf16_rn(xv.x - bf16_to_f(h0));
    u16 h1 = bf16_rn(xv.y); aH[p4+1][ch ^ (((p4+1)&7)<<3)] = h1; aL[p4+1][ch ^ (((p4+1)&7)<<3)] = bf16_rn(xv.y - bf16_to_f(h1));
    u16 h2 = bf16_rn(xv.z); aH[p4+2][ch ^ (((p4+2)&7)<<3)] = h2; aL[p4+2][ch ^ (((p4+2)&7)<<3)] = bf16_rn(xv.z - bf16_to_f(h2));
    u16 h3 = bf16_rn(xv.w); aH[p4+3][ch ^ (((p4+3)&7)<<3)] = h3; aL[p4+3][ch ^ (((p4+3)&7)<<3)] = bf16_rn(xv.w - bf16_to_f(h3));
  }
  __syncthreads();

  int l = t & 63, wv_ = t >> 6;
  int pi = l & 15, kg = l >> 4;
  int pos = wv_ * 16 + pi;
  int swz = (pi & 7) << 3;

  v4f acc[4];
  #pragma unroll
  for (int i = 0; i < 4; ++i) acc[i] = v4f{0.f, 0.f, 0.f, 0.f};

  #pragma unroll
  for (int kt = 0; kt < 2; ++kt) {
    int ka = (kg * 8 + kt * 32) ^ swz;
    v8s ah = *(const v8s*)&aH[pos][ka];
    v8s al = *(const v8s*)&aL[pos][ka];
    #pragma unroll
    for (int ct = 0; ct < 4; ++ct) {
      int o = ct * 16 + pi;
      v8s bh = *(const v8s*)&wH[o][ka];
      v8s bl = *(const v8s*)&wL[o][ka];
      acc[ct] = __builtin_amdgcn_mfma_f32_16x16x32_bf16(ah, bh, acc[ct], 0, 0, 0);
      acc[ct] = __builtin_amdgcn_mfma_f32_16x16x32_bf16(ah, bl, acc[ct], 0, 0, 0);
      acc[ct] = __builtin_amdgcn_mfma_f32_16x16x32_bf16(al, bh, acc[ct], 0, 0, 0);
    }
  }

  #pragma unroll
  for (int ct = 0; ct < 4; ++ct) {
    int o = ct * 16 + pi;
    size_t base = ((size_t)(b * 64 + o)) * S_LEN + s0 + wv_ * 16 + kg * 4;
    float4 x4 = *(const float4*)&x1[base];
    float cbv = cbl[o];
    float y0 = acc[ct][0] + x4.x + cbv;
    float y1 = acc[ct][1] + x4.y + cbv;
    float y2 = acc[ct][2] + x4.z + cbv;
    float y3 = acc[ct][3] + x4.w + cbv;
    if (do_gelu) { y0 = gelu_f(y0); y1 = gelu_f(y1); y2 = gelu_f(y2); y3 = gelu_f(y3); }
    float4 y4 = make_float4(y0, y1, y2, y3);
    *(float4*)&v[base] = y4;
  }
}

// ---------------------------------------------------------------- head via MFMA (pre-split W)
__global__ __launch_bounds__(256) void head_mfma(
    const float* __restrict__ v,
    const u16* __restrict__ whH, const u16* __restrict__ whL,
    const float* __restrict__ fc1b, const float* __restrict__ fc2w,
    const float* __restrict__ fc2b, float* __restrict__ out)
{
  __shared__ u16 aH[64][64], aL[64][64];
  __shared__ u16 wH[128][64], wL[128][64];
  __shared__ float f1b[128], f2w[128];
  int b  = blockIdx.x >> 7;
  int s0 = (blockIdx.x & 127) << 6;
  int t  = threadIdx.x;

  {
    const v8s* srcH = (const v8s*)whH;
    const v8s* srcL = (const v8s*)whL;
    v8s* dstH = (v8s*)&wH[0][0];
    v8s* dstL = (v8s*)&wL[0][0];
    #pragma unroll
    for (int r = 0; r < 4; ++r) {
      dstH[t + 256 * r] = srcH[t + 256 * r];
      dstL[t + 256 * r] = srcL[t + 256 * r];
    }
  }
  if (t < 128) { f1b[t] = fc1b[t]; f2w[t] = fc2w[t]; }

  #pragma unroll
  for (int r = 0; r < 4; ++r) {
    int idx = t + 256 * r;
    int ch = idx >> 4, p4 = (idx & 15) << 2;
    float4 xv = *(const float4*)&v[((size_t)(b * 64 + ch)) * S_LEN + s0 + p4];
    u16 h0 = bf16_rn(xv.x); aH[p4+0][ch ^ (((p4+0)&7)<<3)] = h0; aL[p4+0][ch ^ (((p4+0)&7)<<3)] = bf16_rn(xv.x - bf16_to_f(h0));
    u16 h1 = bf16_rn(xv.y); aH[p4+1][ch ^ (((p4+1)&7)<<3)] = h1; aL[p4+1][ch ^ (((p4+1)&7)<<3)] = bf16_rn(xv.y - bf16_to_f(h1));
    u16 h2 = bf16_rn(xv.z); aH[p4+2][ch ^ (((p4+2)&7)<<3)] = h2; aL[p4+2][ch ^ (((p4+2)&7)<<3)] = bf16_rn(xv.z - bf16_to_f(h2));
    u16 h3 = bf16_rn(xv.w); aH[p4+3][ch ^ (((p4+3)&7)<<3)] = h3; aL[p4+3][ch ^ (((p4+3)&7)<<3)] = bf16_rn(xv.w - bf16_to_f(h3));
  }
  __syncthreads();

  int l = t & 63, wv_ = t >> 6;
  int pi = l & 15, kg = l >> 4;
  int pos = wv_ * 16 + pi;
  int swz = (pi & 7) << 3;

  v4f acc[8];
  #pragma unroll
  for (int i = 0; i < 8; ++i) acc[i] = v4f{0.f, 0.f, 0.f, 0.f};

  #pragma unroll
  for (int kt = 0; kt < 2; ++kt) {
    int ka = (kg * 8 + kt * 32) ^ swz;
    v8s ah = *(const v8s*)&aH[pos][ka];
    v8s al = *(const v8s*)&aL[pos][ka];
    #pragma unroll
    for (int ct = 0; ct < 8; ++ct) {
      int j = ct * 16 + pi;
      v8s bh = *(const v8s*)&wH[j][ka];
      v8s bl = *(const v8s*)&wL[j][ka];
      acc[ct] = __builtin_amdgcn_mfma_f32_16x16x32_bf16(ah, bh, acc[ct], 0, 0, 0);
      acc[ct] = __builtin_amdgcn_mfma_f32_16x16x32_bf16(ah, bl, acc[ct], 0, 0, 0);
      acc[ct] = __builtin_amdgcn_mfma_f32_16x16x32_bf16(al, bh, acc[ct], 0, 0, 0);
    }
  }

  float part[4] = {0.f, 0.f, 0.f, 0.f};
  #pragma unroll
  for (int ct = 0; ct < 8; ++ct) {
    int j = ct * 16 + pi;
    float bias = f1b[j], f2 = f2w[j];
    #pragma unroll
    for (int r = 0; r < 4; ++r) {
      float d = acc[ct][r] + bias;
      part[r] += f2 * gelu_f(d);
    }
  }
  #pragma unroll
  for (int r = 0; r < 4; ++r) {
    part[r] += __shfl_xor(part[r], 1, 16);
    part[r] += __shfl_xor(part[r], 2, 16);
    part[r] += __shfl_xor(part[r], 4, 16);
    part[r] += __shfl_xor(part[r], 8, 16);
  }
  if (pi == 0) {
    float b2 = fc2b[0];
    float4 o4 = make_float4(part[0] + b2, part[1] + b2, part[2] + b2, part[3] + b2);
    *(float4*)&out[(size_t)b * S_LEN + s0 + wv_ * 16 + kg * 4] = o4;
  }
}

// ----------------------------------------------------------------
extern "C" void kernel_launch(void* const* d_in, const int* in_sizes, int n_in,
                              void* d_out, int out_size, void* d_ws, size_t ws_size,
                              hipStream_t stream) {
  const float* x    = (const float*)d_in[0];
  const float* fc0w = (const float*)d_in[1];
  const float* fc0b = (const float*)d_in[2];
  const float* w1   = (const float*)d_in[3];
  const float* w2   = (const float*)d_in[4];
  const float* cw   = (const float*)d_in[5];
  const float* cb   = (const float*)d_in[6];
  const float* fc1w = (const float*)d_in[7];
  const float* fc1b = (const float*)d_in[8];
  const float* fc2w = (const float*)d_in[9];
  const float* fc2b = (const float*)d_in[10];
  float* out = (float*)d_out;

  float* ws     = (float*)d_ws;
  float* v      = ws;
  float* lo1    = v      + (size_t)BC * S_LEN;
  float* x1     = lo1    + (size_t)BC * L1_STR;
  float* highs  = x1     + (size_t)BC * S_LEN;
  float* yl_raw = highs  + (size_t)BC * HTOT;
  float* lo_f   = yl_raw + (size_t)BC * MODES;
  float* lo_i   = lo_f   + (size_t)BC * LO_STR;
  u16*   whH    = (u16*)(lo_i + (size_t)BC * LO_STR);
  u16*   whL    = whH + 8192;
  u16*   wcH    = whL + 8192;
  u16*   wcL    = wcH + 16384;
  size_t needed = (size_t)((char*)(wcL + 16384) - (char*)ws);
  if (ws_size < needed) return;

  prep_split<<<96, 256, 0, stream>>>(fc1w, cw, whH, whL, wcH, wcL);
  fc0_kernel<<<1024, 256, 0, stream>>>(x, fc0w, fc0b, v);

  for (int i = 0; i < 4; ++i) {
    const float* w1l = w1 + (size_t)i * 64 * 64 * MODES;
    const float* w2l = w2 + (size_t)i * 64 * 64 * MODES;
    dwt_big<<<BC * 4, 256, 0, stream>>>(v, highs, lo_f);
    dwt_small<<<BC, 256, 0, stream>>>(lo_f, highs, yl_raw);
    idwt_small<<<BC, 256, 0, stream>>>(yl_raw, highs, w1l, w2l, lo_i);
    idwt_mid<<<BC * 4, 256, 0, stream>>>(lo_i, highs, lo1);
    final_lvl<<<BC * 4, 256, 0, stream>>>(lo1, highs, x1);
    pw_mfma<<<4096, 256, 0, stream>>>(x1, v, wcH + i * 4096, wcL + i * 4096, cb + i * 64, (i < 3) ? 1 : 0);
  }

  head_mfma<<<4096, 256, 0, stream>>>(v, whH, whL, fc1b, fc2w, fc2b, out);
}

// Round 15
// 591.933 us; speedup vs baseline: 1.1025x; 1.1025x over previous
//
#include <hip/hip_runtime.h>
#include <cmath>

#define BC 2048          // B*W sequences
#define S_LEN 8192
#define MODES 42
// padded pyramid: L1@0(4101) L2@4104(2056) L3@6160(1033) L4@7196(522)
//                 L5@7720(266) L6@7988(138) L7@8128(74) L8@8204(42)
#define HTOT 8248
#define LO_STR 1036      // padded stride for the 1033-long lo buffers

static constexpr float C_LO[12] = {
  0.11154074335008017f, 0.4946238903983854f, 0.7511339080215775f,
  0.3152503517092432f, -0.22626469396516913f, -0.12976686756709563f,
  0.09750160558707936f, 0.02752286553001629f, -0.031582039318031156f,
  0.0005538422009938016f, 0.004777257511010651f, -0.00107730108499558f };

__device__ __forceinline__ float rec_lo_c(int k){ return C_LO[k]; }
__device__ __forceinline__ float rec_hi_c(int k){ float v = C_LO[11-k]; return (k&1)? -v : v; }
__device__ __forceinline__ float dec_lo_c(int k){ return C_LO[11-k]; }
__device__ __forceinline__ float dec_hi_c(int k){ float v = C_LO[k];    return (k&1)?  v : -v; }

// branchless erf (Abramowitz-Stegun 7.1.26, |err|<=1.5e-7)
__device__ __forceinline__ float erf_fast(float x){
  float ax = fabsf(x);
  float t  = __fdividef(1.0f, 1.0f + 0.3275911f * ax);
  float p  = ((((1.061405429f * t - 1.453152027f) * t) + 1.421413741f) * t - 0.284496736f) * t + 0.254829592f;
  float y  = 1.0f - p * t * __expf(-ax * ax);
  return copysignf(y, x);
}
__device__ __forceinline__ float gelu_f(float x){
  return 0.5f * x * (1.0f + erf_fast(x * 0.70710678118654752440f));
}

__device__ __forceinline__ int reflect_i(int t, int n){
  t = (t < 0) ? (-1 - t) : t;
  t = (t >= n) ? (2 * n - 1 - t) : t;
  return t;
}

__device__ __forceinline__ unsigned short bf16_rn(float x){
  unsigned int b = __float_as_uint(x);
  b += 0x7FFF + ((b >> 16) & 1);
  return (unsigned short)(b >> 16);
}
__device__ __forceinline__ float bf16_to_f(unsigned short h){
  return __uint_as_float(((unsigned int)h) << 16);
}

typedef short  v8s __attribute__((ext_vector_type(8)));
typedef float  v4f __attribute__((ext_vector_type(4)));
typedef unsigned short u16;

__device__ __forceinline__ void ld3f4(float* w, const float* s){
  *(float4*)&w[0] = *(const float4*)&s[0];
  *(float4*)&w[4] = *(const float4*)&s[4];
  *(float4*)&w[8] = *(const float4*)&s[8];
}
__device__ __forceinline__ void ld5f4(float* w, const float* s){
  *(float4*)&w[0]  = *(const float4*)&s[0];
  *(float4*)&w[4]  = *(const float4*)&s[4];
  *(float4*)&w[8]  = *(const float4*)&s[8];
  *(float4*)&w[12] = *(const float4*)&s[12];
  *(float4*)&w[16] = *(const float4*)&s[16];
}
__device__ __forceinline__ void ld4f2(float* w, const float* s){
  *(float2*)&w[0] = *(const float2*)&s[0];
  *(float2*)&w[2] = *(const float2*)&s[2];
  *(float2*)&w[4] = *(const float2*)&s[4];
  *(float2*)&w[6] = *(const float2*)&s[6];
}

// zero-pad staging: dst[j] = (0<=g0+j<n) ? src[g0+j] : 0 ; g0%4==0, cnt%4==0
__device__ __forceinline__ void stage_g(float* dst, const float* src, int g0, int cnt, int n){
  for (int j4 = threadIdx.x; j4 < (cnt >> 2); j4 += 256) {
    int g = g0 + 4 * j4;
    float4 val;
    if (g >= 0 && g + 3 < n) val = *(const float4*)&src[g];
    else {
      val.x = (g   >= 0 && g   < n) ? src[g]   : 0.f;
      val.y = (g+1 >= 0 && g+1 < n) ? src[g+1] : 0.f;
      val.z = (g+2 >= 0 && g+2 < n) ? src[g+2] : 0.f;
      val.w = (g+3 >= 0 && g+3 < n) ? src[g+3] : 0.f;
    }
    *(float4*)&dst[4*j4] = val;
  }
}

// per-sub (64-thread) band staging
__device__ __forceinline__ void stage_band4_64(float* dst, const float* src, int len, int alloc, int t64){
  for (int i4 = t64; i4 < (alloc >> 2); i4 += 64) {
    int i = 4 * i4;
    float4 v;
    if (i + 3 < len) v = *(const float4*)&src[i];
    else {
      v.x = (i   < len) ? src[i]   : 0.f;
      v.y = (i+1 < len) ? src[i+1] : 0.f;
      v.z = (i+2 < len) ? src[i+2] : 0.f;
      v.w = (i+3 < len) ? src[i+3] : 0.f;
    }
    *(float4*)&dst[i] = v;
  }
}

// 4 IDWT outputs m=u0..u0+3 from windows wl/wh[8]; tap base SH + (d>>1)
template<int SH>
__device__ __forceinline__ void idwt4s(const float* wl, const float* wh, float* o4){
  #pragma unroll
  for (int d = 0; d < 4; ++d) {
    const int q = SH + (d >> 1);
    float acc = 0.f;
    if (d & 1) {
      #pragma unroll
      for (int i = 0; i < 6; ++i) acc += wl[q+i]*dec_lo_c(2*i)   + wh[q+i]*dec_hi_c(2*i);
    } else {
      #pragma unroll
      for (int i = 0; i < 6; ++i) acc += wl[q+i]*dec_lo_c(2*i+1) + wh[q+i]*dec_hi_c(2*i+1);
    }
    o4[d] = acc;
  }
}

// ---------------------------------------------------------------- prep: split weights to hi/lo bf16 in swizzled layout
__global__ __launch_bounds__(256) void prep_split(
    const float* __restrict__ fc1w, const float* __restrict__ cw,
    u16* __restrict__ whH, u16* __restrict__ whL,
    u16* __restrict__ wcH, u16* __restrict__ wcL)
{
  int i = blockIdx.x * 256 + threadIdx.x;
  if (i < 8192) {
    int c = i >> 7, j = i & 127;
    float wv = fc1w[i];
    u16 h = bf16_rn(wv);
    float lo = wv - bf16_to_f(h);
    int cs = c ^ ((j & 7) << 3);
    whH[j * 64 + cs] = h; whL[j * 64 + cs] = bf16_rn(lo);
  }
  int k = i - 8192;
  if (k >= 0 && k < 16384) {
    int l = k >> 12, r = k & 4095;
    int c = r >> 6, o = r & 63;
    float wv = cw[k];
    u16 h = bf16_rn(wv);
    float lo = wv - bf16_to_f(h);
    int cs = c ^ ((o & 7) << 3);
    wcH[l * 4096 + o * 64 + cs] = h; wcL[l * 4096 + o * 64 + cs] = bf16_rn(lo);
  }
}

// ---------------------------------------------------------------- fc0 (coalesced float4)
__global__ __launch_bounds__(256) void fc0_kernel(
    const float* __restrict__ x, const float* __restrict__ w,
    const float* __restrict__ bias, float* __restrict__ v)
{
  int p = blockIdx.x * 256 + threadIdx.x;     // (b, c, s4)
  int s4 = (p & 2047) << 2;
  int c  = (p >> 11) & 63;
  int b  = p >> 17;
  float4 xv = *(const float4*)&x[b * S_LEN + s4];
  float w0 = w[c], w1v = w[64 + c], bc = bias[c];
  const float inv = 1.0f / 8191.0f;
  float4 o;
  o.x = xv.x * w0 + (float)(s4    ) * inv * w1v + bc;
  o.y = xv.y * w0 + (float)(s4 + 1) * inv * w1v + bc;
  o.z = xv.z * w0 + (float)(s4 + 2) * inv * w1v + bc;
  o.w = xv.w * w0 + (float)(s4 + 3) * inv * w1v + bc;
  *(float4*)&v[((size_t)(b * 64 + c)) * S_LEN + s4] = o;
}

// ---------------------------------------------------------------- DWT big: 8192->4101->2056->1033, 4 chunks/seq
__global__ __launch_bounds__(256) void dwt_big(
    const float* __restrict__ vin, float* __restrict__ highs, float* __restrict__ lo_f)
{
  __shared__ alignas(16) float sVE[1096], sVO[1096];
  __shared__ alignas(16) float sL1Eb[548], sL1Ob[548];   // +4 front pad
  __shared__ alignas(16) float sL2E[276], sL2O[276];
  float* sL1E = sL1Eb + 4;
  float* sL1O = sL1Ob + 4;

  int seq = blockIdx.x >> 2, c = blockIdx.x & 3;
  const float* src = vin + (size_t)seq * S_LEN;
  float* hseq = highs + (size_t)seq * HTOT;
  int tid = threadIdx.x;

  int g0 = 2080 * c - 76;
  for (int j4 = tid; j4 < 545; j4 += 256) {
    int g = g0 + 4 * j4;
    float4 val;
    if (g >= 0 && g + 3 < 8192) val = *(const float4*)&src[g];
    else {
      val.x = src[reflect_i(g,   8192)];
      val.y = src[reflect_i(g+1, 8192)];
      val.z = src[reflect_i(g+2, 8192)];
      val.w = src[reflect_i(g+3, 8192)];
    }
    *(float2*)&sVE[2*j4] = make_float2(val.x, val.z);
    *(float2*)&sVO[2*j4] = make_float2(val.y, val.w);
  }
  __syncthreads();

  {
    int base1m = 1040 * c - 32;
    int uh1 = (c < 3) ? 1072 : 1013;
    for (int u0 = 4 * tid; u0 < 1084; u0 += 1024) {
      float we[12], wo[12];
      ld3f4(we, &sVE[u0]); ld3f4(wo, &sVO[u0]);
      float lo4[4], hi4[4];
      #pragma unroll
      for (int d = 0; d < 4; ++d) {
        float alo = 0.f, ahi = 0.f;
        #pragma unroll
        for (int j = 0; j < 6; ++j) {
          float e = we[d+1+j], oo = wo[d+1+j];
          alo += e * rec_lo_c(2*j) + oo * rec_lo_c(2*j+1);
          ahi += e * rec_hi_c(2*j) + oo * rec_hi_c(2*j+1);
        }
        lo4[d] = alo; hi4[d] = ahi;
      }
      *(float2*)&sL1E[u0 >> 1] = make_float2(lo4[0], lo4[2]);
      *(float2*)&sL1O[u0 >> 1] = make_float2(lo4[1], lo4[3]);
      if (u0 >= 32 && u0 + 3 < uh1) {
        *(float4*)&hseq[base1m + u0] = make_float4(hi4[0], hi4[1], hi4[2], hi4[3]);
      } else {
        #pragma unroll
        for (int d = 0; d < 4; ++d) {
          int u = u0 + d;
          if (u >= 32 && u < uh1) hseq[base1m + u] = hi4[d];
        }
      }
    }
  }
  __syncthreads();
  if (c == 0) {
    for (int u = tid; u < 32; u += 256) {
      int j = 63 - u;
      float v = (j & 1) ? sL1O[j >> 1] : sL1E[j >> 1];
      if (u & 1) sL1O[u >> 1] = v; else sL1E[u >> 1] = v;
    }
  }
  if (c == 3) {
    for (int u = 1013 + tid; u < 1084; u += 256) {
      int j = 2025 - u;
      float v = (j & 1) ? sL1O[j >> 1] : sL1E[j >> 1];
      if (u & 1) sL1O[u >> 1] = v; else sL1E[u >> 1] = v;
    }
  }
  __syncthreads();

  {
    int base2m = 520 * c - 12;
    int uh2 = (c < 3) ? 532 : 508;
    for (int u0 = 4 * tid; u0 < 536; u0 += 1024) {
      float we[12], wo[12];
      ld3f4(we, &sL1E[u0 - 4]); ld3f4(wo, &sL1O[u0 - 4]);
      float lo4[4], hi4[4];
      #pragma unroll
      for (int d = 0; d < 4; ++d) {
        float alo = 0.f, ahi = 0.f;
        #pragma unroll
        for (int j = 0; j < 6; ++j) {
          float e = we[d+3+j], oo = wo[d+3+j];
          alo += e * rec_lo_c(2*j) + oo * rec_lo_c(2*j+1);
          ahi += e * rec_hi_c(2*j) + oo * rec_hi_c(2*j+1);
        }
        lo4[d] = alo; hi4[d] = ahi;
      }
      *(float2*)&sL2E[u0 >> 1] = make_float2(lo4[0], lo4[2]);
      *(float2*)&sL2O[u0 >> 1] = make_float2(lo4[1], lo4[3]);
      if (u0 >= 12 && u0 < uh2)
        *(float4*)&hseq[4104 + base2m + u0] = make_float4(hi4[0], hi4[1], hi4[2], hi4[3]);
    }
  }
  __syncthreads();
  if (c == 0) {
    for (int u = tid; u < 12; u += 256) {
      int j = 23 - u;
      float v = (j & 1) ? sL2O[j >> 1] : sL2E[j >> 1];
      if (u & 1) sL2O[u >> 1] = v; else sL2E[u >> 1] = v;
    }
  }
  if (c == 3) {
    for (int u = 508 + tid; u < 536; u += 256) {
      int j = 1015 - u;
      float v = (j & 1) ? sL2O[j >> 1] : sL2E[j >> 1];
      if (u & 1) sL2O[u >> 1] = v; else sL2E[u >> 1] = v;
    }
  }
  __syncthreads();

  for (int u0 = 4 * tid; u0 < 260; u0 += 1024) {
    float we[12], wo[12];
    ld3f4(we, &sL2E[u0]); ld3f4(wo, &sL2O[u0]);
    float lo4[4], hi4[4];
    #pragma unroll
    for (int d = 0; d < 4; ++d) {
      float alo = 0.f, ahi = 0.f;
      #pragma unroll
      for (int j = 0; j < 6; ++j) {
        float e = we[d+1+j], oo = wo[d+1+j];
        alo += e * rec_lo_c(2*j) + oo * rec_lo_c(2*j+1);
        ahi += e * rec_hi_c(2*j) + oo * rec_hi_c(2*j+1);
      }
      lo4[d] = alo; hi4[d] = ahi;
    }
    int m0 = 260 * c + u0;
    if (m0 + 3 < 1033) {
      *(float4*)&lo_f[(size_t)seq * LO_STR + m0] = make_float4(lo4[0], lo4[1], lo4[2], lo4[3]);
      *(float4*)&hseq[6160 + m0] = make_float4(hi4[0], hi4[1], hi4[2], hi4[3]);
    } else {
      #pragma unroll
      for (int d = 0; d < 4; ++d) {
        int m = m0 + d;
        if (m < 1033 && u0 + d < 260) {
          lo_f[(size_t)seq * LO_STR + m] = lo4[d];
          hseq[6160 + m] = hi4[d];
        }
      }
    }
  }
}

// ---------------------------------------------------------------- DWT small x4: 1033->...->42, 4 seqs/block (1 wave each)
__device__ __forceinline__ void dwt_lvl_v64(const float* in, int n, float* out, int outn, float* hg, int t64)
{
  for (int u0 = 4*t64; u0 < outn; u0 += 256) {
    bool fast = (u0 >= 8) && (2*u0 + 7 < n) && (u0 + 3 < outn);
    if (fast) {
      float w[20];
      ld5f4(w, &in[2*u0 - 12]);
      #pragma unroll
      for (int d = 0; d < 4; ++d) {
        float alo = 0.f, ahi = 0.f;
        #pragma unroll
        for (int k = 0; k < 12; ++k) {
          float x = w[2*d + 2 + k];
          alo += x * rec_lo_c(k); ahi += x * rec_hi_c(k);
        }
        out[u0+d] = alo; hg[u0+d] = ahi;
      }
    } else {
      for (int d = 0; d < 4; ++d) {
        if (u0 + d < outn) {
          float alo = 0.f, ahi = 0.f;
          #pragma unroll
          for (int k = 0; k < 12; ++k) {
            float x = in[reflect_i(2*(u0+d) + k - 10, n)];
            alo += x * rec_lo_c(k); ahi += x * rec_hi_c(k);
          }
          out[u0+d] = alo; hg[u0+d] = ahi;
        }
      }
    }
  }
  __syncthreads();
}

__global__ __launch_bounds__(256) void dwt_small(
    const float* __restrict__ lo_f, float* __restrict__ highs, float* __restrict__ yl)
{
  __shared__ alignas(16) float A[4][1040], Bb[4][528];
  int sub = threadIdx.x >> 6, t64 = threadIdx.x & 63;
  int seq = blockIdx.x * 4 + sub;
  const float* src = lo_f + (size_t)seq * LO_STR;
  float* hseq = highs + (size_t)seq * HTOT;
  float* As = A[sub];
  float* Bs = Bb[sub];
  for (int i = 4*t64; i < 1033; i += 256) {
    if (i + 3 < 1033) *(float4*)&As[i] = *(const float4*)&src[i];
    else { for (int d = 0; d < 4; ++d) if (i + d < 1033) As[i+d] = src[i+d]; }
  }
  __syncthreads();
  dwt_lvl_v64(As, 1033, Bs, 522, hseq + 7196, t64);
  dwt_lvl_v64(Bs, 522, As, 266, hseq + 7720, t64);
  dwt_lvl_v64(As, 266, Bs, 138, hseq + 7988, t64);
  dwt_lvl_v64(Bs, 138, As, 74,  hseq + 8128, t64);
  dwt_lvl_v64(As, 74,  Bs, 42,  hseq + 8204, t64);
  for (int m = t64; m < MODES; m += 64) yl[seq * MODES + m] = Bs[m];
}

// ---------------------------------------------------------------- IDWT small x4 + fused channel mix (serial, validated)
__device__ __forceinline__ void idwt_lvl4_64(const float* lo, const float* h, float* out, int outn, int t64)
{
  for (int u0 = 4*t64; u0 < outn; u0 += 256) {
    int q = u0 >> 1;
    float wl[8], wh[8];
    ld4f2(wl, &lo[q]); ld4f2(wh, &h[q]);
    float o4[4]; idwt4s<0>(wl, wh, o4);
    if (u0 + 3 < outn) *(float4*)&out[u0] = make_float4(o4[0], o4[1], o4[2], o4[3]);
    else { for (int d = 0; d < 4; ++d) if (u0 + d < outn) out[u0+d] = o4[d]; }
  }
  __syncthreads();
}

__global__ __launch_bounds__(256) void idwt_small(
    const float* __restrict__ yl_raw, const float* __restrict__ highs,
    const float* __restrict__ w1l, const float* __restrict__ w2l,
    float* __restrict__ lo_i)
{
  // per-sub bands: yl@0(48) yh@48(48) h74@96(80) h138@176(144) h266@320(272) h522@592(528)
  __shared__ alignas(16) float bands[4][1120], wa[4][272], wb[4][528];
  int sub = threadIdx.x >> 6, t64 = threadIdx.x & 63;
  int seq = blockIdx.x * 4 + sub;
  int b = seq >> 6, o = seq & 63;
  const float* hseq = highs + (size_t)seq * HTOT;
  float* bs = bands[sub];
  float* was = wa[sub];
  float* wbs = wb[sub];

  stage_band4_64(bs + 96,  hseq + 8128, 74, 80, t64);
  stage_band4_64(bs + 176, hseq + 7988, 138, 144, t64);
  stage_band4_64(bs + 320, hseq + 7720, 266, 272, t64);
  stage_band4_64(bs + 592, hseq + 7196, 522, 528, t64);

  if (t64 >= 42 && t64 < 48) { bs[t64] = 0.f; bs[48 + t64] = 0.f; }
  if (t64 < 42) {
    const float* yr = yl_raw + (size_t)b * 2688 + t64;               // + i*42
    const float* hh = highs + (size_t)(b * 64) * HTOT + 8204 + t64;  // + i*HTOT
    const float* wl = w1l + o * 42 + t64;                             // + i*2688
    const float* wh = w2l + o * 42 + t64;
    float accl = 0.f, acch = 0.f;
    #pragma unroll 4
    for (int i = 0; i < 64; ++i) {
      accl += yr[i * 42] * wl[i * 2688];
      acch += hh[(size_t)i * HTOT] * wh[i * 2688];
    }
    bs[t64] = accl; bs[48 + t64] = acch;
  }
  __syncthreads();

  idwt_lvl4_64(bs + 0,   bs + 48,  was, 74, t64);
  idwt_lvl4_64(was,      bs + 96,  wbs, 138, t64);
  idwt_lvl4_64(wbs,      bs + 176, was, 266, t64);
  idwt_lvl4_64(was,      bs + 320, wbs, 522, t64);

  for (int u0 = 4 * t64; u0 < 1033; u0 += 256) {
    int q = u0 >> 1;
    float wl[8], wh[8];
    ld4f2(wl, &wbs[q]); ld4f2(wh, &bs[592 + q]);
    float o4[4]; idwt4s<0>(wl, wh, o4);
    float* dst = lo_i + (size_t)seq * LO_STR + u0;
    if (u0 + 3 < 1033) *(float4*)&dst[0] = make_float4(o4[0], o4[1], o4[2], o4[3]);
    else { for (int d = 0; d < 4; ++d) if (u0 + d < 1033) dst[d] = o4[d]; }
  }
}

// ---------------------------------------------------------------- IDWT big: 1033->2056->4101->8192, 4 chunks/seq (round-9 validated)
__global__ __launch_bounds__(256) void idwt_big(
    const float* __restrict__ lo_i, const float* __restrict__ highs, float* __restrict__ x1)
{
  __shared__ alignas(16) float sL3[288], sH3[288], sL2[544], sH2[544], sL1[1048], sH1[1048];
  int seq = blockIdx.x >> 2, c = blockIdx.x & 3;
  const float* hseq = highs + (size_t)seq * HTOT;
  const float* l3   = lo_i + (size_t)seq * LO_STR;
  int g3 = 256*c - 4, g2 = 512*c - 4, g1 = 1024*c - 4;
  int t = threadIdx.x;

  stage_g(sL3, l3,          g3, 288, 1033);
  stage_g(sH3, hseq + 6160, g3, 288, 1033);
  stage_g(sH2, hseq + 4104, g2, 544, 2056);
  stage_g(sH1, hseq,        g1, 1048, 4101);
  __syncthreads();

  // s5: m = (512c-2)+u, u in [0,536)
  for (int u0 = 4 * t; u0 < 536; u0 += 1024) {
    int q = u0 >> 1;
    float wl[8], wh[8];
    ld4f2(wl, &sL3[q + 2]); ld4f2(wh, &sH3[q + 2]);
    float o4[4]; idwt4s<1>(wl, wh, o4);
    #pragma unroll
    for (int d = 0; d < 4; ++d) {
      int m = 512*c - 2 + u0 + d;
      o4[d] = (m >= 0 && m < 2056) ? o4[d] : 0.f;
    }
    *(float2*)&sL2[u0 + 2] = make_float2(o4[0], o4[1]);
    *(float2*)&sL2[u0 + 4] = make_float2(o4[2], o4[3]);
  }
  __syncthreads();

  // s6: m = (1024c-2)+u, u in [0,1040)
  for (int u0 = 4 * t; u0 < 1040; u0 += 1024) {
    int q = u0 >> 1;
    float wl[8], wh[8];
    ld4f2(wl, &sL2[q + 2]); ld4f2(wh, &sH2[q + 2]);
    float o4[4]; idwt4s<1>(wl, wh, o4);
    #pragma unroll
    for (int d = 0; d < 4; ++d) {
      int m = 1024*c - 2 + u0 + d;
      o4[d] = (m >= 0 && m < 4101) ? o4[d] : 0.f;
    }
    *(float2*)&sL1[u0 + 2] = make_float2(o4[0], o4[1]);
    *(float2*)&sL1[u0 + 4] = make_float2(o4[2], o4[3]);
  }
  __syncthreads();

  // s7: m = 2048c+u, u in [0,2048)
  for (int u0 = 4 * t; u0 < 2048; u0 += 1024) {
    int q = u0 >> 1;
    float wl[8], wh[8];
    ld4f2(wl, &sL1[q + 4]); ld4f2(wh, &sH1[q + 4]);
    float o4[4]; idwt4s<0>(wl, wh, o4);
    *(float4*)&x1[(size_t)seq * S_LEN + 2048*c + u0] = make_float4(o4[0], o4[1], o4[2], o4[3]);
  }
}

// ---------------------------------------------------------------- layer pointwise via MFMA (round-9 validated, reads x1)
__global__ __launch_bounds__(256) void pw_mfma(
    const float* __restrict__ x1, float* v,
    const u16* __restrict__ wcH, const u16* __restrict__ wcL,
    const float* __restrict__ cb, int do_gelu)
{
  __shared__ u16 aH[64][64], aL[64][64];
  __shared__ u16 wH[64][64], wL[64][64];
  __shared__ float cbl[64];
  int b  = blockIdx.x >> 7;
  int s0 = (blockIdx.x & 127) << 6;
  int t  = threadIdx.x;

  {
    const v8s* srcH = (const v8s*)wcH;
    const v8s* srcL = (const v8s*)wcL;
    v8s* dstH = (v8s*)&wH[0][0];
    v8s* dstL = (v8s*)&wL[0][0];
    #pragma unroll
    for (int r = 0; r < 2; ++r) {
      dstH[t + 256 * r] = srcH[t + 256 * r];
      dstL[t + 256 * r] = srcL[t + 256 * r];
    }
  }
  if (t < 64) cbl[t] = cb[t];

  #pragma unroll
  for (int r = 0; r < 4; ++r) {
    int idx = t + 256 * r;
    int ch = idx >> 4, p4 = (idx & 15) << 2;
    float4 xv = *(const float4*)&v[((size_t)(b * 64 + ch)) * S_LEN + s0 + p4];
    u16 h0 = bf16_rn(xv.x); aH[p4+0][ch ^ (((p4+0)&7)<<3)] = h0; aL[p4+0][ch ^ (((p4+0)&7)<<3)] = bf16_rn(xv.x - bf16_to_f(h0));
    u16 h1 = bf16_rn(xv.y); aH[p4+1][ch ^ (((p4+1)&7)<<3)] = h1; aL[p4+1][ch ^ (((p4+1)&7)<<3)] = bf16_rn(xv.y - bf16_to_f(h1));
    u16 h2 = bf16_rn(xv.z); aH[p4+2][ch ^ (((p4+2)&7)<<3)] = h2; aL[p4+2][ch ^ (((p4+2)&7)<<3)] = bf16_rn(xv.z - bf16_to_f(h2));
    u16 h3 = bf16_rn(xv.w); aH[p4+3][ch ^ (((p4+3)&7)<<3)] = h3; aL[p4+3][ch ^ (((p4+3)&7)<<3)] = bf16_rn(xv.w - bf16_to_f(h3));
  }
  __syncthreads();

  int l = t & 63, wv_ = t >> 6;
  int pi = l & 15, kg = l >> 4;
  int pos = wv_ * 16 + pi;
  int swz = (pi & 7) << 3;

  v4f acc[4];
  #pragma unroll
  for (int i = 0; i < 4; ++i) acc[i] = v4f{0.f, 0.f, 0.f, 0.f};

  #pragma unroll
  for (int kt = 0; kt < 2; ++kt) {
    int ka = (kg * 8 + kt * 32) ^ swz;
    v8s ah = *(const v8s*)&aH[pos][ka];
    v8s al = *(const v8s*)&aL[pos][ka];
    #pragma unroll
    for (int ct = 0; ct < 4; ++ct) {
      int o = ct * 16 + pi;
      v8s bh = *(const v8s*)&wH[o][ka];
      v8s bl = *(const v8s*)&wL[o][ka];
      acc[ct] = __builtin_amdgcn_mfma_f32_16x16x32_bf16(ah, bh, acc[ct], 0, 0, 0);
      acc[ct] = __builtin_amdgcn_mfma_f32_16x16x32_bf16(ah, bl, acc[ct], 0, 0, 0);
      acc[ct] = __builtin_amdgcn_mfma_f32_16x16x32_bf16(al, bh, acc[ct], 0, 0, 0);
    }
  }

  #pragma unroll
  for (int ct = 0; ct < 4; ++ct) {
    int o = ct * 16 + pi;
    size_t base = ((size_t)(b * 64 + o)) * S_LEN + s0 + wv_ * 16 + kg * 4;
    float4 x4 = *(const float4*)&x1[base];
    float cbv = cbl[o];
    float y0 = acc[ct][0] + x4.x + cbv;
    float y1 = acc[ct][1] + x4.y + cbv;
    float y2 = acc[ct][2] + x4.z + cbv;
    float y3 = acc[ct][3] + x4.w + cbv;
    if (do_gelu) { y0 = gelu_f(y0); y1 = gelu_f(y1); y2 = gelu_f(y2); y3 = gelu_f(y3); }
    float4 y4 = make_float4(y0, y1, y2, y3);
    *(float4*)&v[base] = y4;
  }
}

// ---------------------------------------------------------------- head via MFMA (pre-split W)
__global__ __launch_bounds__(256) void head_mfma(
    const float* __restrict__ v,
    const u16* __restrict__ whH, const u16* __restrict__ whL,
    const float* __restrict__ fc1b, const float* __restrict__ fc2w,
    const float* __restrict__ fc2b, float* __restrict__ out)
{
  __shared__ u16 aH[64][64], aL[64][64];
  __shared__ u16 wH[128][64], wL[128][64];
  __shared__ float f1b[128], f2w[128];
  int b  = blockIdx.x >> 7;
  int s0 = (blockIdx.x & 127) << 6;
  int t  = threadIdx.x;

  {
    const v8s* srcH = (const v8s*)whH;
    const v8s* srcL = (const v8s*)whL;
    v8s* dstH = (v8s*)&wH[0][0];
    v8s* dstL = (v8s*)&wL[0][0];
    #pragma unroll
    for (int r = 0; r < 4; ++r) {
      dstH[t + 256 * r] = srcH[t + 256 * r];
      dstL[t + 256 * r] = srcL[t + 256 * r];
    }
  }
  if (t < 128) { f1b[t] = fc1b[t]; f2w[t] = fc2w[t]; }

  #pragma unroll
  for (int r = 0; r < 4; ++r) {
    int idx = t + 256 * r;
    int ch = idx >> 4, p4 = (idx & 15) << 2;
    float4 xv = *(const float4*)&v[((size_t)(b * 64 + ch)) * S_LEN + s0 + p4];
    u16 h0 = bf16_rn(xv.x); aH[p4+0][ch ^ (((p4+0)&7)<<3)] = h0; aL[p4+0][ch ^ (((p4+0)&7)<<3)] = bf16_rn(xv.x - bf16_to_f(h0));
    u16 h1 = bf16_rn(xv.y); aH[p4+1][ch ^ (((p4+1)&7)<<3)] = h1; aL[p4+1][ch ^ (((p4+1)&7)<<3)] = bf16_rn(xv.y - bf16_to_f(h1));
    u16 h2 = bf16_rn(xv.z); aH[p4+2][ch ^ (((p4+2)&7)<<3)] = h2; aL[p4+2][ch ^ (((p4+2)&7)<<3)] = bf16_rn(xv.z - bf16_to_f(h2));
    u16 h3 = bf16_rn(xv.w); aH[p4+3][ch ^ (((p4+3)&7)<<3)] = h3; aL[p4+3][ch ^ (((p4+3)&7)<<3)] = bf16_rn(xv.w - bf16_to_f(h3));
  }
  __syncthreads();

  int l = t & 63, wv_ = t >> 6;
  int pi = l & 15, kg = l >> 4;
  int pos = wv_ * 16 + pi;
  int swz = (pi & 7) << 3;

  v4f acc[8];
  #pragma unroll
  for (int i = 0; i < 8; ++i) acc[i] = v4f{0.f, 0.f, 0.f, 0.f};

  #pragma unroll
  for (int kt = 0; kt < 2; ++kt) {
    int ka = (kg * 8 + kt * 32) ^ swz;
    v8s ah = *(const v8s*)&aH[pos][ka];
    v8s al = *(const v8s*)&aL[pos][ka];
    #pragma unroll
    for (int ct = 0; ct < 8; ++ct) {
      int j = ct * 16 + pi;
      v8s bh = *(const v8s*)&wH[j][ka];
      v8s bl = *(const v8s*)&wL[j][ka];
      acc[ct] = __builtin_amdgcn_mfma_f32_16x16x32_bf16(ah, bh, acc[ct], 0, 0, 0);
      acc[ct] = __builtin_amdgcn_mfma_f32_16x16x32_bf16(ah, bl, acc[ct], 0, 0, 0);
      acc[ct] = __builtin_amdgcn_mfma_f32_16x16x32_bf16(al, bh, acc[ct], 0, 0, 0);
    }
  }

  float part[4] = {0.f, 0.f, 0.f, 0.f};
  #pragma unroll
  for (int ct = 0; ct < 8; ++ct) {
    int j = ct * 16 + pi;
    float bias = f1b[j], f2 = f2w[j];
    #pragma unroll
    for (int r = 0; r < 4; ++r) {
      float d = acc[ct][r] + bias;
      part[r] += f2 * gelu_f(d);
    }
  }
  #pragma unroll
  for (int r = 0; r < 4; ++r) {
    part[r] += __shfl_xor(part[r], 1, 16);
    part[r] += __shfl_xor(part[r], 2, 16);
    part[r] += __shfl_xor(part[r], 4, 16);
    part[r] += __shfl_xor(part[r], 8, 16);
  }
  if (pi == 0) {
    float b2 = fc2b[0];
    float4 o4 = make_float4(part[0] + b2, part[1] + b2, part[2] + b2, part[3] + b2);
    *(float4*)&out[(size_t)b * S_LEN + s0 + wv_ * 16 + kg * 4] = o4;
  }
}

// ----------------------------------------------------------------
extern "C" void kernel_launch(void* const* d_in, const int* in_sizes, int n_in,
                              void* d_out, int out_size, void* d_ws, size_t ws_size,
                              hipStream_t stream) {
  const float* x    = (const float*)d_in[0];
  const float* fc0w = (const float*)d_in[1];
  const float* fc0b = (const float*)d_in[2];
  const float* w1   = (const float*)d_in[3];
  const float* w2   = (const float*)d_in[4];
  const float* cw   = (const float*)d_in[5];
  const float* cb   = (const float*)d_in[6];
  const float* fc1w = (const float*)d_in[7];
  const float* fc1b = (const float*)d_in[8];
  const float* fc2w = (const float*)d_in[9];
  const float* fc2b = (const float*)d_in[10];
  float* out = (float*)d_out;

  float* ws     = (float*)d_ws;
  float* v      = ws;
  float* x1     = v      + (size_t)BC * S_LEN;
  float* highs  = x1     + (size_t)BC * S_LEN;
  float* yl_raw = highs  + (size_t)BC * HTOT;
  float* lo_f   = yl_raw + (size_t)BC * MODES;
  float* lo_i   = lo_f   + (size_t)BC * LO_STR;
  u16*   whH    = (u16*)(lo_i + (size_t)BC * LO_STR);
  u16*   whL    = whH + 8192;
  u16*   wcH    = whL + 8192;
  u16*   wcL    = wcH + 16384;
  size_t needed = (size_t)((char*)(wcL + 16384) - (char*)ws);
  if (ws_size < needed) return;

  prep_split<<<96, 256, 0, stream>>>(fc1w, cw, whH, whL, wcH, wcL);
  fc0_kernel<<<16384, 256, 0, stream>>>(x, fc0w, fc0b, v);

  for (int i = 0; i < 4; ++i) {
    const float* w1l = w1 + (size_t)i * 64 * 64 * MODES;
    const float* w2l = w2 + (size_t)i * 64 * 64 * MODES;
    dwt_big<<<BC * 4, 256, 0, stream>>>(v, highs, lo_f);
    dwt_small<<<BC / 4, 256, 0, stream>>>(lo_f, highs, yl_raw);
    idwt_small<<<BC / 4, 256, 0, stream>>>(yl_raw, highs, w1l, w2l, lo_i);
    idwt_big<<<BC * 4, 256, 0, stream>>>(lo_i, highs, x1);
    pw_mfma<<<4096, 256, 0, stream>>>(x1, v, wcH + i * 4096, wcL + i * 4096, cb + i * 64, (i < 3) ? 1 : 0);
  }

  head_mfma<<<4096, 256, 0, stream>>>(v, whH, whL, fc1b, fc2w, fc2b, out);
}

// Round 16
// 580.169 us; speedup vs baseline: 1.1248x; 1.0203x over previous
//
#include <hip/hip_runtime.h>
#include <cmath>

#define BC 2048          // B*W sequences
#define S_LEN 8192
#define MODES 42
// padded pyramid: L1@0(4101) L2@4104(2056) L3@6160(1033) L4@7196(522)
//                 L5@7720(266) L6@7988(138) L7@8128(74) L8@8204(42)
#define HTOT 8248
#define LO_STR 1036      // padded stride for the 1033-long lo buffers

static constexpr float C_LO[12] = {
  0.11154074335008017f, 0.4946238903983854f, 0.7511339080215775f,
  0.3152503517092432f, -0.22626469396516913f, -0.12976686756709563f,
  0.09750160558707936f, 0.02752286553001629f, -0.031582039318031156f,
  0.0005538422009938016f, 0.004777257511010651f, -0.00107730108499558f };

__device__ __forceinline__ float rec_lo_c(int k){ return C_LO[k]; }
__device__ __forceinline__ float rec_hi_c(int k){ float v = C_LO[11-k]; return (k&1)? -v : v; }
__device__ __forceinline__ float dec_lo_c(int k){ return C_LO[11-k]; }
__device__ __forceinline__ float dec_hi_c(int k){ float v = C_LO[k];    return (k&1)?  v : -v; }

// branchless erf (Abramowitz-Stegun 7.1.26, |err|<=1.5e-7)
__device__ __forceinline__ float erf_fast(float x){
  float ax = fabsf(x);
  float t  = __fdividef(1.0f, 1.0f + 0.3275911f * ax);
  float p  = ((((1.061405429f * t - 1.453152027f) * t) + 1.421413741f) * t - 0.284496736f) * t + 0.254829592f;
  float y  = 1.0f - p * t * __expf(-ax * ax);
  return copysignf(y, x);
}
__device__ __forceinline__ float gelu_f(float x){
  return 0.5f * x * (1.0f + erf_fast(x * 0.70710678118654752440f));
}

__device__ __forceinline__ int reflect_i(int t, int n){
  t = (t < 0) ? (-1 - t) : t;
  t = (t >= n) ? (2 * n - 1 - t) : t;
  return t;
}

__device__ __forceinline__ unsigned short bf16_rn(float x){
  unsigned int b = __float_as_uint(x);
  b += 0x7FFF + ((b >> 16) & 1);
  return (unsigned short)(b >> 16);
}
__device__ __forceinline__ float bf16_to_f(unsigned short h){
  return __uint_as_float(((unsigned int)h) << 16);
}

typedef short  v8s __attribute__((ext_vector_type(8)));
typedef float  v4f __attribute__((ext_vector_type(4)));
typedef unsigned short u16;

__device__ __forceinline__ void ld3f4(float* w, const float* s){
  *(float4*)&w[0] = *(const float4*)&s[0];
  *(float4*)&w[4] = *(const float4*)&s[4];
  *(float4*)&w[8] = *(const float4*)&s[8];
}
__device__ __forceinline__ void ld5f4(float* w, const float* s){
  *(float4*)&w[0]  = *(const float4*)&s[0];
  *(float4*)&w[4]  = *(const float4*)&s[4];
  *(float4*)&w[8]  = *(const float4*)&s[8];
  *(float4*)&w[12] = *(const float4*)&s[12];
  *(float4*)&w[16] = *(const float4*)&s[16];
}
__device__ __forceinline__ void ld4f2(float* w, const float* s){
  *(float2*)&w[0] = *(const float2*)&s[0];
  *(float2*)&w[2] = *(const float2*)&s[2];
  *(float2*)&w[4] = *(const float2*)&s[4];
  *(float2*)&w[6] = *(const float2*)&s[6];
}

// zero-pad staging: dst[j] = (0<=g0+j<n) ? src[g0+j] : 0 ; g0%4==0, cnt%4==0
__device__ __forceinline__ void stage_g(float* dst, const float* src, int g0, int cnt, int n){
  for (int j4 = threadIdx.x; j4 < (cnt >> 2); j4 += 256) {
    int g = g0 + 4 * j4;
    float4 val;
    if (g >= 0 && g + 3 < n) val = *(const float4*)&src[g];
    else {
      val.x = (g   >= 0 && g   < n) ? src[g]   : 0.f;
      val.y = (g+1 >= 0 && g+1 < n) ? src[g+1] : 0.f;
      val.z = (g+2 >= 0 && g+2 < n) ? src[g+2] : 0.f;
      val.w = (g+3 >= 0 && g+3 < n) ? src[g+3] : 0.f;
    }
    *(float4*)&dst[4*j4] = val;
  }
}

// per-sub (64-thread) band staging
__device__ __forceinline__ void stage_band4_64(float* dst, const float* src, int len, int alloc, int t64){
  for (int i4 = t64; i4 < (alloc >> 2); i4 += 64) {
    int i = 4 * i4;
    float4 v;
    if (i + 3 < len) v = *(const float4*)&src[i];
    else {
      v.x = (i   < len) ? src[i]   : 0.f;
      v.y = (i+1 < len) ? src[i+1] : 0.f;
      v.z = (i+2 < len) ? src[i+2] : 0.f;
      v.w = (i+3 < len) ? src[i+3] : 0.f;
    }
    *(float4*)&dst[i] = v;
  }
}

// 4 IDWT outputs m=u0..u0+3 from windows wl/wh[8]; tap base SH + (d>>1)
template<int SH>
__device__ __forceinline__ void idwt4s(const float* wl, const float* wh, float* o4){
  #pragma unroll
  for (int d = 0; d < 4; ++d) {
    const int q = SH + (d >> 1);
    float acc = 0.f;
    if (d & 1) {
      #pragma unroll
      for (int i = 0; i < 6; ++i) acc += wl[q+i]*dec_lo_c(2*i)   + wh[q+i]*dec_hi_c(2*i);
    } else {
      #pragma unroll
      for (int i = 0; i < 6; ++i) acc += wl[q+i]*dec_lo_c(2*i+1) + wh[q+i]*dec_hi_c(2*i+1);
    }
    o4[d] = acc;
  }
}

// ---------------------------------------------------------------- prep: split weights to hi/lo bf16 in swizzled layout
__global__ __launch_bounds__(256) void prep_split(
    const float* __restrict__ fc1w, const float* __restrict__ cw,
    u16* __restrict__ whH, u16* __restrict__ whL,
    u16* __restrict__ wcH, u16* __restrict__ wcL)
{
  int i = blockIdx.x * 256 + threadIdx.x;
  if (i < 8192) {
    int c = i >> 7, j = i & 127;
    float wv = fc1w[i];
    u16 h = bf16_rn(wv);
    float lo = wv - bf16_to_f(h);
    int cs = c ^ ((j & 7) << 3);
    whH[j * 64 + cs] = h; whL[j * 64 + cs] = bf16_rn(lo);
  }
  int k = i - 8192;
  if (k >= 0 && k < 16384) {
    int l = k >> 12, r = k & 4095;
    int c = r >> 6, o = r & 63;
    float wv = cw[k];
    u16 h = bf16_rn(wv);
    float lo = wv - bf16_to_f(h);
    int cs = c ^ ((o & 7) << 3);
    wcH[l * 4096 + o * 64 + cs] = h; wcL[l * 4096 + o * 64 + cs] = bf16_rn(lo);
  }
}

// ---------------------------------------------------------------- fc0 (coalesced float4)
__global__ __launch_bounds__(256) void fc0_kernel(
    const float* __restrict__ x, const float* __restrict__ w,
    const float* __restrict__ bias, float* __restrict__ v)
{
  int p = blockIdx.x * 256 + threadIdx.x;     // (b, c, s4)
  int s4 = (p & 2047) << 2;
  int c  = (p >> 11) & 63;
  int b  = p >> 17;
  float4 xv = *(const float4*)&x[b * S_LEN + s4];
  float w0 = w[c], w1v = w[64 + c], bc = bias[c];
  const float inv = 1.0f / 8191.0f;
  float4 o;
  o.x = xv.x * w0 + (float)(s4    ) * inv * w1v + bc;
  o.y = xv.y * w0 + (float)(s4 + 1) * inv * w1v + bc;
  o.z = xv.z * w0 + (float)(s4 + 2) * inv * w1v + bc;
  o.w = xv.w * w0 + (float)(s4 + 3) * inv * w1v + bc;
  *(float4*)&v[((size_t)(b * 64 + c)) * S_LEN + s4] = o;
}

// ---------------------------------------------------------------- DWT big: 8192->4101->2056->1033, 4 chunks/seq
__global__ __launch_bounds__(256) void dwt_big(
    const float* __restrict__ vin, float* __restrict__ highs, float* __restrict__ lo_f)
{
  __shared__ alignas(16) float sVE[1096], sVO[1096];
  __shared__ alignas(16) float sL1Eb[548], sL1Ob[548];   // +4 front pad
  __shared__ alignas(16) float sL2E[276], sL2O[276];
  float* sL1E = sL1Eb + 4;
  float* sL1O = sL1Ob + 4;

  int seq = blockIdx.x >> 2, c = blockIdx.x & 3;
  const float* src = vin + (size_t)seq * S_LEN;
  float* hseq = highs + (size_t)seq * HTOT;
  int tid = threadIdx.x;

  int g0 = 2080 * c - 76;
  for (int j4 = tid; j4 < 545; j4 += 256) {
    int g = g0 + 4 * j4;
    float4 val;
    if (g >= 0 && g + 3 < 8192) val = *(const float4*)&src[g];
    else {
      val.x = src[reflect_i(g,   8192)];
      val.y = src[reflect_i(g+1, 8192)];
      val.z = src[reflect_i(g+2, 8192)];
      val.w = src[reflect_i(g+3, 8192)];
    }
    *(float2*)&sVE[2*j4] = make_float2(val.x, val.z);
    *(float2*)&sVO[2*j4] = make_float2(val.y, val.w);
  }
  __syncthreads();

  {
    int base1m = 1040 * c - 32;
    int uh1 = (c < 3) ? 1072 : 1013;
    for (int u0 = 4 * tid; u0 < 1084; u0 += 1024) {
      float we[12], wo[12];
      ld3f4(we, &sVE[u0]); ld3f4(wo, &sVO[u0]);
      float lo4[4], hi4[4];
      #pragma unroll
      for (int d = 0; d < 4; ++d) {
        float alo = 0.f, ahi = 0.f;
        #pragma unroll
        for (int j = 0; j < 6; ++j) {
          float e = we[d+1+j], oo = wo[d+1+j];
          alo += e * rec_lo_c(2*j) + oo * rec_lo_c(2*j+1);
          ahi += e * rec_hi_c(2*j) + oo * rec_hi_c(2*j+1);
        }
        lo4[d] = alo; hi4[d] = ahi;
      }
      *(float2*)&sL1E[u0 >> 1] = make_float2(lo4[0], lo4[2]);
      *(float2*)&sL1O[u0 >> 1] = make_float2(lo4[1], lo4[3]);
      if (u0 >= 32 && u0 + 3 < uh1) {
        *(float4*)&hseq[base1m + u0] = make_float4(hi4[0], hi4[1], hi4[2], hi4[3]);
      } else {
        #pragma unroll
        for (int d = 0; d < 4; ++d) {
          int u = u0 + d;
          if (u >= 32 && u < uh1) hseq[base1m + u] = hi4[d];
        }
      }
    }
  }
  __syncthreads();
  if (c == 0) {
    for (int u = tid; u < 32; u += 256) {
      int j = 63 - u;
      float v = (j & 1) ? sL1O[j >> 1] : sL1E[j >> 1];
      if (u & 1) sL1O[u >> 1] = v; else sL1E[u >> 1] = v;
    }
  }
  if (c == 3) {
    for (int u = 1013 + tid; u < 1084; u += 256) {
      int j = 2025 - u;
      float v = (j & 1) ? sL1O[j >> 1] : sL1E[j >> 1];
      if (u & 1) sL1O[u >> 1] = v; else sL1E[u >> 1] = v;
    }
  }
  __syncthreads();

  {
    int base2m = 520 * c - 12;
    int uh2 = (c < 3) ? 532 : 508;
    for (int u0 = 4 * tid; u0 < 536; u0 += 1024) {
      float we[12], wo[12];
      ld3f4(we, &sL1E[u0 - 4]); ld3f4(wo, &sL1O[u0 - 4]);
      float lo4[4], hi4[4];
      #pragma unroll
      for (int d = 0; d < 4; ++d) {
        float alo = 0.f, ahi = 0.f;
        #pragma unroll
        for (int j = 0; j < 6; ++j) {
          float e = we[d+3+j], oo = wo[d+3+j];
          alo += e * rec_lo_c(2*j) + oo * rec_lo_c(2*j+1);
          ahi += e * rec_hi_c(2*j) + oo * rec_hi_c(2*j+1);
        }
        lo4[d] = alo; hi4[d] = ahi;
      }
      *(float2*)&sL2E[u0 >> 1] = make_float2(lo4[0], lo4[2]);
      *(float2*)&sL2O[u0 >> 1] = make_float2(lo4[1], lo4[3]);
      if (u0 >= 12 && u0 < uh2)
        *(float4*)&hseq[4104 + base2m + u0] = make_float4(hi4[0], hi4[1], hi4[2], hi4[3]);
    }
  }
  __syncthreads();
  if (c == 0) {
    for (int u = tid; u < 12; u += 256) {
      int j = 23 - u;
      float v = (j & 1) ? sL2O[j >> 1] : sL2E[j >> 1];
      if (u & 1) sL2O[u >> 1] = v; else sL2E[u >> 1] = v;
    }
  }
  if (c == 3) {
    for (int u = 508 + tid; u < 536; u += 256) {
      int j = 1015 - u;
      float v = (j & 1) ? sL2O[j >> 1] : sL2E[j >> 1];
      if (u & 1) sL2O[u >> 1] = v; else sL2E[u >> 1] = v;
    }
  }
  __syncthreads();

  for (int u0 = 4 * tid; u0 < 260; u0 += 1024) {
    float we[12], wo[12];
    ld3f4(we, &sL2E[u0]); ld3f4(wo, &sL2O[u0]);
    float lo4[4], hi4[4];
    #pragma unroll
    for (int d = 0; d < 4; ++d) {
      float alo = 0.f, ahi = 0.f;
      #pragma unroll
      for (int j = 0; j < 6; ++j) {
        float e = we[d+1+j], oo = wo[d+1+j];
        alo += e * rec_lo_c(2*j) + oo * rec_lo_c(2*j+1);
        ahi += e * rec_hi_c(2*j) + oo * rec_hi_c(2*j+1);
      }
      lo4[d] = alo; hi4[d] = ahi;
    }
    int m0 = 260 * c + u0;
    if (m0 + 3 < 1033) {
      *(float4*)&lo_f[(size_t)seq * LO_STR + m0] = make_float4(lo4[0], lo4[1], lo4[2], lo4[3]);
      *(float4*)&hseq[6160 + m0] = make_float4(hi4[0], hi4[1], hi4[2], hi4[3]);
    } else {
      #pragma unroll
      for (int d = 0; d < 4; ++d) {
        int m = m0 + d;
        if (m < 1033 && u0 + d < 260) {
          lo_f[(size_t)seq * LO_STR + m] = lo4[d];
          hseq[6160 + m] = hi4[d];
        }
      }
    }
  }
}

// ---------------------------------------------------------------- DWT small x4: 1033->...->42, 4 seqs/block (1 wave each)
__device__ __forceinline__ void dwt_lvl_v64(const float* in, int n, float* out, int outn, float* hg, int t64)
{
  for (int u0 = 4*t64; u0 < outn; u0 += 256) {
    bool fast = (u0 >= 8) && (2*u0 + 7 < n) && (u0 + 3 < outn);
    if (fast) {
      float w[20];
      ld5f4(w, &in[2*u0 - 12]);
      #pragma unroll
      for (int d = 0; d < 4; ++d) {
        float alo = 0.f, ahi = 0.f;
        #pragma unroll
        for (int k = 0; k < 12; ++k) {
          float x = w[2*d + 2 + k];
          alo += x * rec_lo_c(k); ahi += x * rec_hi_c(k);
        }
        out[u0+d] = alo; hg[u0+d] = ahi;
      }
    } else {
      for (int d = 0; d < 4; ++d) {
        if (u0 + d < outn) {
          float alo = 0.f, ahi = 0.f;
          #pragma unroll
          for (int k = 0; k < 12; ++k) {
            float x = in[reflect_i(2*(u0+d) + k - 10, n)];
            alo += x * rec_lo_c(k); ahi += x * rec_hi_c(k);
          }
          out[u0+d] = alo; hg[u0+d] = ahi;
        }
      }
    }
  }
  __syncthreads();
}

__global__ __launch_bounds__(256) void dwt_small(
    const float* __restrict__ lo_f, float* __restrict__ highs, float* __restrict__ yl)
{
  __shared__ alignas(16) float A[4][1040], Bb[4][528];
  int sub = threadIdx.x >> 6, t64 = threadIdx.x & 63;
  int seq = blockIdx.x * 4 + sub;
  const float* src = lo_f + (size_t)seq * LO_STR;
  float* hseq = highs + (size_t)seq * HTOT;
  float* As = A[sub];
  float* Bs = Bb[sub];
  for (int i = 4*t64; i < 1033; i += 256) {
    if (i + 3 < 1033) *(float4*)&As[i] = *(const float4*)&src[i];
    else { for (int d = 0; d < 4; ++d) if (i + d < 1033) As[i+d] = src[i+d]; }
  }
  __syncthreads();
  dwt_lvl_v64(As, 1033, Bs, 522, hseq + 7196, t64);
  dwt_lvl_v64(Bs, 522, As, 266, hseq + 7720, t64);
  dwt_lvl_v64(As, 266, Bs, 138, hseq + 7988, t64);
  dwt_lvl_v64(Bs, 138, As, 74,  hseq + 8128, t64);
  dwt_lvl_v64(As, 74,  Bs, 42,  hseq + 8204, t64);
  for (int m = t64; m < MODES; m += 64) yl[seq * MODES + m] = Bs[m];
}

// ---------------------------------------------------------------- IDWT small x4 + fused channel mix (serial, validated)
__device__ __forceinline__ void idwt_lvl4_64(const float* lo, const float* h, float* out, int outn, int t64)
{
  for (int u0 = 4*t64; u0 < outn; u0 += 256) {
    int q = u0 >> 1;
    float wl[8], wh[8];
    ld4f2(wl, &lo[q]); ld4f2(wh, &h[q]);
    float o4[4]; idwt4s<0>(wl, wh, o4);
    if (u0 + 3 < outn) *(float4*)&out[u0] = make_float4(o4[0], o4[1], o4[2], o4[3]);
    else { for (int d = 0; d < 4; ++d) if (u0 + d < outn) out[u0+d] = o4[d]; }
  }
  __syncthreads();
}

__global__ __launch_bounds__(256) void idwt_small(
    const float* __restrict__ yl_raw, const float* __restrict__ highs,
    const float* __restrict__ w1l, const float* __restrict__ w2l,
    float* __restrict__ lo_i)
{
  // per-sub bands: yl@0(48) yh@48(48) h74@96(80) h138@176(144) h266@320(272) h522@592(528)
  __shared__ alignas(16) float bands[4][1120], wa[4][272], wb[4][528];
  int sub = threadIdx.x >> 6, t64 = threadIdx.x & 63;
  int seq = blockIdx.x * 4 + sub;
  int b = seq >> 6, o = seq & 63;
  const float* hseq = highs + (size_t)seq * HTOT;
  float* bs = bands[sub];
  float* was = wa[sub];
  float* wbs = wb[sub];

  stage_band4_64(bs + 96,  hseq + 8128, 74, 80, t64);
  stage_band4_64(bs + 176, hseq + 7988, 138, 144, t64);
  stage_band4_64(bs + 320, hseq + 7720, 266, 272, t64);
  stage_band4_64(bs + 592, hseq + 7196, 522, 528, t64);

  if (t64 >= 42 && t64 < 48) { bs[t64] = 0.f; bs[48 + t64] = 0.f; }
  if (t64 < 42) {
    const float* yr = yl_raw + (size_t)b * 2688 + t64;               // + i*42
    const float* hh = highs + (size_t)(b * 64) * HTOT + 8204 + t64;  // + i*HTOT
    const float* wl = w1l + o * 42 + t64;                             // + i*2688
    const float* wh = w2l + o * 42 + t64;
    float accl = 0.f, acch = 0.f;
    #pragma unroll 4
    for (int i = 0; i < 64; ++i) {
      accl += yr[i * 42] * wl[i * 2688];
      acch += hh[(size_t)i * HTOT] * wh[i * 2688];
    }
    bs[t64] = accl; bs[48 + t64] = acch;
  }
  __syncthreads();

  idwt_lvl4_64(bs + 0,   bs + 48,  was, 74, t64);
  idwt_lvl4_64(was,      bs + 96,  wbs, 138, t64);
  idwt_lvl4_64(wbs,      bs + 176, was, 266, t64);
  idwt_lvl4_64(was,      bs + 320, wbs, 522, t64);

  for (int u0 = 4 * t64; u0 < 1033; u0 += 256) {
    int q = u0 >> 1;
    float wl[8], wh[8];
    ld4f2(wl, &wbs[q]); ld4f2(wh, &bs[592 + q]);
    float o4[4]; idwt4s<0>(wl, wh, o4);
    float* dst = lo_i + (size_t)seq * LO_STR + u0;
    if (u0 + 3 < 1033) *(float4*)&dst[0] = make_float4(o4[0], o4[1], o4[2], o4[3]);
    else { for (int d = 0; d < 4; ++d) if (u0 + d < 1033) dst[d] = o4[d]; }
  }
}

// ---------------------------------------------------------------- IDWT big: 1033->2056->4101->8192, 4 chunks/seq (round-9 validated)
__global__ __launch_bounds__(256) void idwt_big(
    const float* __restrict__ lo_i, const float* __restrict__ highs, float* __restrict__ x1)
{
  __shared__ alignas(16) float sL3[288], sH3[288], sL2[544], sH2[544], sL1[1048], sH1[1048];
  int seq = blockIdx.x >> 2, c = blockIdx.x & 3;
  const float* hseq = highs + (size_t)seq * HTOT;
  const float* l3   = lo_i + (size_t)seq * LO_STR;
  int g3 = 256*c - 4, g2 = 512*c - 4, g1 = 1024*c - 4;
  int t = threadIdx.x;

  stage_g(sL3, l3,          g3, 288, 1033);
  stage_g(sH3, hseq + 6160, g3, 288, 1033);
  stage_g(sH2, hseq + 4104, g2, 544, 2056);
  stage_g(sH1, hseq,        g1, 1048, 4101);
  __syncthreads();

  for (int u0 = 4 * t; u0 < 536; u0 += 1024) {
    int q = u0 >> 1;
    float wl[8], wh[8];
    ld4f2(wl, &sL3[q + 2]); ld4f2(wh, &sH3[q + 2]);
    float o4[4]; idwt4s<1>(wl, wh, o4);
    #pragma unroll
    for (int d = 0; d < 4; ++d) {
      int m = 512*c - 2 + u0 + d;
      o4[d] = (m >= 0 && m < 2056) ? o4[d] : 0.f;
    }
    *(float2*)&sL2[u0 + 2] = make_float2(o4[0], o4[1]);
    *(float2*)&sL2[u0 + 4] = make_float2(o4[2], o4[3]);
  }
  __syncthreads();

  for (int u0 = 4 * t; u0 < 1040; u0 += 1024) {
    int q = u0 >> 1;
    float wl[8], wh[8];
    ld4f2(wl, &sL2[q + 2]); ld4f2(wh, &sH2[q + 2]);
    float o4[4]; idwt4s<1>(wl, wh, o4);
    #pragma unroll
    for (int d = 0; d < 4; ++d) {
      int m = 1024*c - 2 + u0 + d;
      o4[d] = (m >= 0 && m < 4101) ? o4[d] : 0.f;
    }
    *(float2*)&sL1[u0 + 2] = make_float2(o4[0], o4[1]);
    *(float2*)&sL1[u0 + 4] = make_float2(o4[2], o4[3]);
  }
  __syncthreads();

  for (int u0 = 4 * t; u0 < 2048; u0 += 1024) {
    int q = u0 >> 1;
    float wl[8], wh[8];
    ld4f2(wl, &sL1[q + 4]); ld4f2(wh, &sH1[q + 4]);
    float o4[4]; idwt4s<0>(wl, wh, o4);
    *(float4*)&x1[(size_t)seq * S_LEN + 2048*c + u0] = make_float4(o4[0], o4[1], o4[2], o4[3]);
  }
}

// ---------------------------------------------------------------- layer pointwise via MFMA (layers 0-2)
__global__ __launch_bounds__(256) void pw_mfma(
    const float* __restrict__ x1, float* v,
    const u16* __restrict__ wcH, const u16* __restrict__ wcL,
    const float* __restrict__ cb)
{
  __shared__ u16 aH[64][64], aL[64][64];
  __shared__ u16 wH[64][64], wL[64][64];
  __shared__ float cbl[64];
  int b  = blockIdx.x >> 7;
  int s0 = (blockIdx.x & 127) << 6;
  int t  = threadIdx.x;

  {
    const v8s* srcH = (const v8s*)wcH;
    const v8s* srcL = (const v8s*)wcL;
    v8s* dstH = (v8s*)&wH[0][0];
    v8s* dstL = (v8s*)&wL[0][0];
    #pragma unroll
    for (int r = 0; r < 2; ++r) {
      dstH[t + 256 * r] = srcH[t + 256 * r];
      dstL[t + 256 * r] = srcL[t + 256 * r];
    }
  }
  if (t < 64) cbl[t] = cb[t];

  #pragma unroll
  for (int r = 0; r < 4; ++r) {
    int idx = t + 256 * r;
    int ch = idx >> 4, p4 = (idx & 15) << 2;
    float4 xv = *(const float4*)&v[((size_t)(b * 64 + ch)) * S_LEN + s0 + p4];
    u16 h0 = bf16_rn(xv.x); aH[p4+0][ch ^ (((p4+0)&7)<<3)] = h0; aL[p4+0][ch ^ (((p4+0)&7)<<3)] = bf16_rn(xv.x - bf16_to_f(h0));
    u16 h1 = bf16_rn(xv.y); aH[p4+1][ch ^ (((p4+1)&7)<<3)] = h1; aL[p4+1][ch ^ (((p4+1)&7)<<3)] = bf16_rn(xv.y - bf16_to_f(h1));
    u16 h2 = bf16_rn(xv.z); aH[p4+2][ch ^ (((p4+2)&7)<<3)] = h2; aL[p4+2][ch ^ (((p4+2)&7)<<3)] = bf16_rn(xv.z - bf16_to_f(h2));
    u16 h3 = bf16_rn(xv.w); aH[p4+3][ch ^ (((p4+3)&7)<<3)] = h3; aL[p4+3][ch ^ (((p4+3)&7)<<3)] = bf16_rn(xv.w - bf16_to_f(h3));
  }
  __syncthreads();

  int l = t & 63, wv_ = t >> 6;
  int pi = l & 15, kg = l >> 4;
  int pos = wv_ * 16 + pi;
  int swz = (pi & 7) << 3;

  v4f acc[4];
  #pragma unroll
  for (int i = 0; i < 4; ++i) acc[i] = v4f{0.f, 0.f, 0.f, 0.f};

  #pragma unroll
  for (int kt = 0; kt < 2; ++kt) {
    int ka = (kg * 8 + kt * 32) ^ swz;
    v8s ah = *(const v8s*)&aH[pos][ka];
    v8s al = *(const v8s*)&aL[pos][ka];
    #pragma unroll
    for (int ct = 0; ct < 4; ++ct) {
      int o = ct * 16 + pi;
      v8s bh = *(const v8s*)&wH[o][ka];
      v8s bl = *(const v8s*)&wL[o][ka];
      acc[ct] = __builtin_amdgcn_mfma_f32_16x16x32_bf16(ah, bh, acc[ct], 0, 0, 0);
      acc[ct] = __builtin_amdgcn_mfma_f32_16x16x32_bf16(ah, bl, acc[ct], 0, 0, 0);
      acc[ct] = __builtin_amdgcn_mfma_f32_16x16x32_bf16(al, bh, acc[ct], 0, 0, 0);
    }
  }

  #pragma unroll
  for (int ct = 0; ct < 4; ++ct) {
    int o = ct * 16 + pi;
    size_t base = ((size_t)(b * 64 + o)) * S_LEN + s0 + wv_ * 16 + kg * 4;
    float4 x4 = *(const float4*)&x1[base];
    float cbv = cbl[o];
    float y0 = gelu_f(acc[ct][0] + x4.x + cbv);
    float y1 = gelu_f(acc[ct][1] + x4.y + cbv);
    float y2 = gelu_f(acc[ct][2] + x4.z + cbv);
    float y3 = gelu_f(acc[ct][3] + x4.w + cbv);
    float4 y4 = make_float4(y0, y1, y2, y3);
    *(float4*)&v[base] = y4;
  }
}

// ---------------------------------------------------------------- fused final layer: pw (no gelu) + head, v never touches HBM
__global__ __launch_bounds__(256) void pw_head_mfma(
    const float* __restrict__ x1, const float* __restrict__ v,
    const u16* __restrict__ wcH, const u16* __restrict__ wcL,
    const float* __restrict__ cb,
    const u16* __restrict__ whH, const u16* __restrict__ whL,
    const float* __restrict__ fc1b, const float* __restrict__ fc2w,
    const float* __restrict__ fc2b, float* __restrict__ out)
{
  __shared__ u16 aH[64][64], aL[64][64];
  __shared__ u16 wH[64][64], wL[64][64];       // cw
  __shared__ u16 hH[128][64], hL[128][64];     // fc1
  __shared__ float cbl[64], f1b[128], f2w[128];
  int b  = blockIdx.x >> 7;
  int s0 = (blockIdx.x & 127) << 6;
  int t  = threadIdx.x;

  {
    const v8s* srcH = (const v8s*)wcH;
    const v8s* srcL = (const v8s*)wcL;
    v8s* dstH = (v8s*)&wH[0][0];
    v8s* dstL = (v8s*)&wL[0][0];
    #pragma unroll
    for (int r = 0; r < 2; ++r) {
      dstH[t + 256 * r] = srcH[t + 256 * r];
      dstL[t + 256 * r] = srcL[t + 256 * r];
    }
  }
  {
    const v8s* srcH = (const v8s*)whH;
    const v8s* srcL = (const v8s*)whL;
    v8s* dstH = (v8s*)&hH[0][0];
    v8s* dstL = (v8s*)&hL[0][0];
    #pragma unroll
    for (int r = 0; r < 4; ++r) {
      dstH[t + 256 * r] = srcH[t + 256 * r];
      dstL[t + 256 * r] = srcL[t + 256 * r];
    }
  }
  if (t < 64) cbl[t] = cb[t];
  if (t < 128) { f1b[t] = fc1b[t]; f2w[t] = fc2w[t]; }

  #pragma unroll
  for (int r = 0; r < 4; ++r) {
    int idx = t + 256 * r;
    int ch = idx >> 4, p4 = (idx & 15) << 2;
    float4 xv = *(const float4*)&v[((size_t)(b * 64 + ch)) * S_LEN + s0 + p4];
    u16 h0 = bf16_rn(xv.x); aH[p4+0][ch ^ (((p4+0)&7)<<3)] = h0; aL[p4+0][ch ^ (((p4+0)&7)<<3)] = bf16_rn(xv.x - bf16_to_f(h0));
    u16 h1 = bf16_rn(xv.y); aH[p4+1][ch ^ (((p4+1)&7)<<3)] = h1; aL[p4+1][ch ^ (((p4+1)&7)<<3)] = bf16_rn(xv.y - bf16_to_f(h1));
    u16 h2 = bf16_rn(xv.z); aH[p4+2][ch ^ (((p4+2)&7)<<3)] = h2; aL[p4+2][ch ^ (((p4+2)&7)<<3)] = bf16_rn(xv.z - bf16_to_f(h2));
    u16 h3 = bf16_rn(xv.w); aH[p4+3][ch ^ (((p4+3)&7)<<3)] = h3; aL[p4+3][ch ^ (((p4+3)&7)<<3)] = bf16_rn(xv.w - bf16_to_f(h3));
  }
  __syncthreads();

  int l = t & 63, wv_ = t >> 6;
  int pi = l & 15, kg = l >> 4;
  int pos = wv_ * 16 + pi;
  int swz = (pi & 7) << 3;

  // ---- pw MFMA (cw mix, K=64)
  v4f acc[4];
  #pragma unroll
  for (int i = 0; i < 4; ++i) acc[i] = v4f{0.f, 0.f, 0.f, 0.f};
  #pragma unroll
  for (int kt = 0; kt < 2; ++kt) {
    int ka = (kg * 8 + kt * 32) ^ swz;
    v8s ah = *(const v8s*)&aH[pos][ka];
    v8s al = *(const v8s*)&aL[pos][ka];
    #pragma unroll
    for (int ct = 0; ct < 4; ++ct) {
      int o = ct * 16 + pi;
      v8s bh = *(const v8s*)&wH[o][ka];
      v8s bl = *(const v8s*)&wL[o][ka];
      acc[ct] = __builtin_amdgcn_mfma_f32_16x16x32_bf16(ah, bh, acc[ct], 0, 0, 0);
      acc[ct] = __builtin_amdgcn_mfma_f32_16x16x32_bf16(ah, bl, acc[ct], 0, 0, 0);
      acc[ct] = __builtin_amdgcn_mfma_f32_16x16x32_bf16(al, bh, acc[ct], 0, 0, 0);
    }
  }
  __syncthreads();   // all MFMA reads of aH/aL complete before overwrite

  // ---- write y = acc + x1 + cb (no gelu, layer 3) back into aH/aL as split bf16
  #pragma unroll
  for (int ct = 0; ct < 4; ++ct) {
    int o = ct * 16 + pi;
    size_t base = ((size_t)(b * 64 + o)) * S_LEN + s0 + wv_ * 16 + kg * 4;
    float4 x4 = *(const float4*)&x1[base];
    float cbv = cbl[o];
    float y[4] = { acc[ct][0] + x4.x + cbv, acc[ct][1] + x4.y + cbv,
                   acc[ct][2] + x4.z + cbv, acc[ct][3] + x4.w + cbv };
    #pragma unroll
    for (int d = 0; d < 4; ++d) {
      int p = wv_ * 16 + kg * 4 + d;
      int cs = o ^ ((p & 7) << 3);
      u16 h = bf16_rn(y[d]);
      aH[p][cs] = h;
      aL[p][cs] = bf16_rn(y[d] - bf16_to_f(h));
    }
  }
  __syncthreads();

  // ---- head MFMA (fc1, K=64, 8 column tiles) — verbatim head_mfma body
  v4f hacc[8];
  #pragma unroll
  for (int i = 0; i < 8; ++i) hacc[i] = v4f{0.f, 0.f, 0.f, 0.f};
  #pragma unroll
  for (int kt = 0; kt < 2; ++kt) {
    int ka = (kg * 8 + kt * 32) ^ swz;
    v8s ah = *(const v8s*)&aH[pos][ka];
    v8s al = *(const v8s*)&aL[pos][ka];
    #pragma unroll
    for (int ct = 0; ct < 8; ++ct) {
      int j = ct * 16 + pi;
      v8s bh = *(const v8s*)&hH[j][ka];
      v8s bl = *(const v8s*)&hL[j][ka];
      hacc[ct] = __builtin_amdgcn_mfma_f32_16x16x32_bf16(ah, bh, hacc[ct], 0, 0, 0);
      hacc[ct] = __builtin_amdgcn_mfma_f32_16x16x32_bf16(ah, bl, hacc[ct], 0, 0, 0);
      hacc[ct] = __builtin_amdgcn_mfma_f32_16x16x32_bf16(al, bh, hacc[ct], 0, 0, 0);
    }
  }

  float part[4] = {0.f, 0.f, 0.f, 0.f};
  #pragma unroll
  for (int ct = 0; ct < 8; ++ct) {
    int j = ct * 16 + pi;
    float bias = f1b[j], f2 = f2w[j];
    #pragma unroll
    for (int r = 0; r < 4; ++r) {
      float d = hacc[ct][r] + bias;
      part[r] += f2 * gelu_f(d);
    }
  }
  #pragma unroll
  for (int r = 0; r < 4; ++r) {
    part[r] += __shfl_xor(part[r], 1, 16);
    part[r] += __shfl_xor(part[r], 2, 16);
    part[r] += __shfl_xor(part[r], 4, 16);
    part[r] += __shfl_xor(part[r], 8, 16);
  }
  if (pi == 0) {
    float b2 = fc2b[0];
    float4 o4 = make_float4(part[0] + b2, part[1] + b2, part[2] + b2, part[3] + b2);
    *(float4*)&out[(size_t)b * S_LEN + s0 + wv_ * 16 + kg * 4] = o4;
  }
}

// ----------------------------------------------------------------
extern "C" void kernel_launch(void* const* d_in, const int* in_sizes, int n_in,
                              void* d_out, int out_size, void* d_ws, size_t ws_size,
                              hipStream_t stream) {
  const float* x    = (const float*)d_in[0];
  const float* fc0w = (const float*)d_in[1];
  const float* fc0b = (const float*)d_in[2];
  const float* w1   = (const float*)d_in[3];
  const float* w2   = (const float*)d_in[4];
  const float* cw   = (const float*)d_in[5];
  const float* cb   = (const float*)d_in[6];
  const float* fc1w = (const float*)d_in[7];
  const float* fc1b = (const float*)d_in[8];
  const float* fc2w = (const float*)d_in[9];
  const float* fc2b = (const float*)d_in[10];
  float* out = (float*)d_out;

  float* ws     = (float*)d_ws;
  float* v      = ws;
  float* x1     = v      + (size_t)BC * S_LEN;
  float* highs  = x1     + (size_t)BC * S_LEN;
  float* yl_raw = highs  + (size_t)BC * HTOT;
  float* lo_f   = yl_raw + (size_t)BC * MODES;
  float* lo_i   = lo_f   + (size_t)BC * LO_STR;
  u16*   whH    = (u16*)(lo_i + (size_t)BC * LO_STR);
  u16*   whL    = whH + 8192;
  u16*   wcH    = whL + 8192;
  u16*   wcL    = wcH + 16384;
  size_t needed = (size_t)((char*)(wcL + 16384) - (char*)ws);
  if (ws_size < needed) return;

  prep_split<<<96, 256, 0, stream>>>(fc1w, cw, whH, whL, wcH, wcL);
  fc0_kernel<<<16384, 256, 0, stream>>>(x, fc0w, fc0b, v);

  for (int i = 0; i < 4; ++i) {
    const float* w1l = w1 + (size_t)i * 64 * 64 * MODES;
    const float* w2l = w2 + (size_t)i * 64 * 64 * MODES;
    dwt_big<<<BC * 4, 256, 0, stream>>>(v, highs, lo_f);
    dwt_small<<<BC / 4, 256, 0, stream>>>(lo_f, highs, yl_raw);
    idwt_small<<<BC / 4, 256, 0, stream>>>(yl_raw, highs, w1l, w2l, lo_i);
    idwt_big<<<BC * 4, 256, 0, stream>>>(lo_i, highs, x1);
    if (i < 3) {
      pw_mfma<<<4096, 256, 0, stream>>>(x1, v, wcH + i * 4096, wcL + i * 4096, cb + i * 64);
    } else {
      pw_head_mfma<<<4096, 256, 0, stream>>>(x1, v, wcH + i * 4096, wcL + i * 4096, cb + i * 64,
                                             whH, whL, fc1b, fc2w, fc2b, out);
    }
  }
}

// Round 17
// 571.434 us; speedup vs baseline: 1.1420x; 1.0153x over previous
//
#include <hip/hip_runtime.h>
#include <cmath>

#define BC 2048          // B*W sequences
#define S_LEN 8192
#define MODES 42
// padded pyramid: L1@0(4101) L2@4104(2056) L3@6160(1033) L4@7196(522)
//                 L5@7720(266) L6@7988(138) L7@8128(74) L8@8204(42)
#define HTOT 8248
#define LO_STR 1036      // padded stride for the 1033-long lo buffers

static constexpr float C_LO[12] = {
  0.11154074335008017f, 0.4946238903983854f, 0.7511339080215775f,
  0.3152503517092432f, -0.22626469396516913f, -0.12976686756709563f,
  0.09750160558707936f, 0.02752286553001629f, -0.031582039318031156f,
  0.0005538422009938016f, 0.004777257511010651f, -0.00107730108499558f };

__device__ __forceinline__ float rec_lo_c(int k){ return C_LO[k]; }
__device__ __forceinline__ float rec_hi_c(int k){ float v = C_LO[11-k]; return (k&1)? -v : v; }
__device__ __forceinline__ float dec_lo_c(int k){ return C_LO[11-k]; }
__device__ __forceinline__ float dec_hi_c(int k){ float v = C_LO[k];    return (k&1)?  v : -v; }

// branchless erf (Abramowitz-Stegun 7.1.26, |err|<=1.5e-7)
__device__ __forceinline__ float erf_fast(float x){
  float ax = fabsf(x);
  float t  = __fdividef(1.0f, 1.0f + 0.3275911f * ax);
  float p  = ((((1.061405429f * t - 1.453152027f) * t) + 1.421413741f) * t - 0.284496736f) * t + 0.254829592f;
  float y  = 1.0f - p * t * __expf(-ax * ax);
  return copysignf(y, x);
}
__device__ __forceinline__ float gelu_f(float x){
  return 0.5f * x * (1.0f + erf_fast(x * 0.70710678118654752440f));
}

__device__ __forceinline__ int reflect_i(int t, int n){
  t = (t < 0) ? (-1 - t) : t;
  t = (t >= n) ? (2 * n - 1 - t) : t;
  return t;
}

__device__ __forceinline__ unsigned short bf16_rn(float x){
  unsigned int b = __float_as_uint(x);
  b += 0x7FFF + ((b >> 16) & 1);
  return (unsigned short)(b >> 16);
}
__device__ __forceinline__ float bf16_to_f(unsigned short h){
  return __uint_as_float(((unsigned int)h) << 16);
}

typedef short  v8s __attribute__((ext_vector_type(8)));
typedef float  v4f __attribute__((ext_vector_type(4)));
typedef unsigned short u16;

__device__ __forceinline__ void ld3f4(float* w, const float* s){
  *(float4*)&w[0] = *(const float4*)&s[0];
  *(float4*)&w[4] = *(const float4*)&s[4];
  *(float4*)&w[8] = *(const float4*)&s[8];
}
__device__ __forceinline__ void ld5f4(float* w, const float* s){
  *(float4*)&w[0]  = *(const float4*)&s[0];
  *(float4*)&w[4]  = *(const float4*)&s[4];
  *(float4*)&w[8]  = *(const float4*)&s[8];
  *(float4*)&w[12] = *(const float4*)&s[12];
  *(float4*)&w[16] = *(const float4*)&s[16];
}
__device__ __forceinline__ void ld4f2(float* w, const float* s){
  *(float2*)&w[0] = *(const float2*)&s[0];
  *(float2*)&w[2] = *(const float2*)&s[2];
  *(float2*)&w[4] = *(const float2*)&s[4];
  *(float2*)&w[6] = *(const float2*)&s[6];
}

// zero-pad staging: dst[j] = (0<=g0+j<n) ? src[g0+j] : 0 ; g0%4==0, cnt%4==0
__device__ __forceinline__ void stage_g(float* dst, const float* src, int g0, int cnt, int n){
  for (int j4 = threadIdx.x; j4 < (cnt >> 2); j4 += 256) {
    int g = g0 + 4 * j4;
    float4 val;
    if (g >= 0 && g + 3 < n) val = *(const float4*)&src[g];
    else {
      val.x = (g   >= 0 && g   < n) ? src[g]   : 0.f;
      val.y = (g+1 >= 0 && g+1 < n) ? src[g+1] : 0.f;
      val.z = (g+2 >= 0 && g+2 < n) ? src[g+2] : 0.f;
      val.w = (g+3 >= 0 && g+3 < n) ? src[g+3] : 0.f;
    }
    *(float4*)&dst[4*j4] = val;
  }
}

// per-sub (64-thread) band staging
__device__ __forceinline__ void stage_band4_64(float* dst, const float* src, int len, int alloc, int t64){
  for (int i4 = t64; i4 < (alloc >> 2); i4 += 64) {
    int i = 4 * i4;
    float4 v;
    if (i + 3 < len) v = *(const float4*)&src[i];
    else {
      v.x = (i   < len) ? src[i]   : 0.f;
      v.y = (i+1 < len) ? src[i+1] : 0.f;
      v.z = (i+2 < len) ? src[i+2] : 0.f;
      v.w = (i+3 < len) ? src[i+3] : 0.f;
    }
    *(float4*)&dst[i] = v;
  }
}

// 4 IDWT outputs m=u0..u0+3 from windows wl/wh[8]; tap base SH + (d>>1)
template<int SH>
__device__ __forceinline__ void idwt4s(const float* wl, const float* wh, float* o4){
  #pragma unroll
  for (int d = 0; d < 4; ++d) {
    const int q = SH + (d >> 1);
    float acc = 0.f;
    if (d & 1) {
      #pragma unroll
      for (int i = 0; i < 6; ++i) acc += wl[q+i]*dec_lo_c(2*i)   + wh[q+i]*dec_hi_c(2*i);
    } else {
      #pragma unroll
      for (int i = 0; i < 6; ++i) acc += wl[q+i]*dec_lo_c(2*i+1) + wh[q+i]*dec_hi_c(2*i+1);
    }
    o4[d] = acc;
  }
}

// ---------------------------------------------------------------- prep: split weights to hi/lo bf16 in swizzled layout
__global__ __launch_bounds__(256) void prep_split(
    const float* __restrict__ fc1w, const float* __restrict__ cw,
    u16* __restrict__ whH, u16* __restrict__ whL,
    u16* __restrict__ wcH, u16* __restrict__ wcL)
{
  int i = blockIdx.x * 256 + threadIdx.x;
  if (i < 8192) {
    int c = i >> 7, j = i & 127;
    float wv = fc1w[i];
    u16 h = bf16_rn(wv);
    float lo = wv - bf16_to_f(h);
    int cs = c ^ ((j & 7) << 3);
    whH[j * 64 + cs] = h; whL[j * 64 + cs] = bf16_rn(lo);
  }
  int k = i - 8192;
  if (k >= 0 && k < 16384) {
    int l = k >> 12, r = k & 4095;
    int c = r >> 6, o = r & 63;
    float wv = cw[k];
    u16 h = bf16_rn(wv);
    float lo = wv - bf16_to_f(h);
    int cs = c ^ ((o & 7) << 3);
    wcH[l * 4096 + o * 64 + cs] = h; wcL[l * 4096 + o * 64 + cs] = bf16_rn(lo);
  }
}

// ---------------------------------------------------------------- fc0 (coalesced float4)
__global__ __launch_bounds__(256) void fc0_kernel(
    const float* __restrict__ x, const float* __restrict__ w,
    const float* __restrict__ bias, float* __restrict__ v)
{
  int p = blockIdx.x * 256 + threadIdx.x;     // (b, c, s4)
  int s4 = (p & 2047) << 2;
  int c  = (p >> 11) & 63;
  int b  = p >> 17;
  float4 xv = *(const float4*)&x[b * S_LEN + s4];
  float w0 = w[c], w1v = w[64 + c], bc = bias[c];
  const float inv = 1.0f / 8191.0f;
  float4 o;
  o.x = xv.x * w0 + (float)(s4    ) * inv * w1v + bc;
  o.y = xv.y * w0 + (float)(s4 + 1) * inv * w1v + bc;
  o.z = xv.z * w0 + (float)(s4 + 2) * inv * w1v + bc;
  o.w = xv.w * w0 + (float)(s4 + 3) * inv * w1v + bc;
  *(float4*)&v[((size_t)(b * 64 + c)) * S_LEN + s4] = o;
}

// ---------------------------------------------------------------- DWT big: 8192->4101->2056->1033, 4 chunks/seq
__global__ __launch_bounds__(256) void dwt_big(
    const float* __restrict__ vin, float* __restrict__ highs, float* __restrict__ lo_f)
{
  __shared__ alignas(16) float sVE[1096], sVO[1096];
  __shared__ alignas(16) float sL1Eb[548], sL1Ob[548];   // +4 front pad
  __shared__ alignas(16) float sL2E[276], sL2O[276];
  float* sL1E = sL1Eb + 4;
  float* sL1O = sL1Ob + 4;

  int seq = blockIdx.x >> 2, c = blockIdx.x & 3;
  const float* src = vin + (size_t)seq * S_LEN;
  float* hseq = highs + (size_t)seq * HTOT;
  int tid = threadIdx.x;

  int g0 = 2080 * c - 76;
  for (int j4 = tid; j4 < 545; j4 += 256) {
    int g = g0 + 4 * j4;
    float4 val;
    if (g >= 0 && g + 3 < 8192) val = *(const float4*)&src[g];
    else {
      val.x = src[reflect_i(g,   8192)];
      val.y = src[reflect_i(g+1, 8192)];
      val.z = src[reflect_i(g+2, 8192)];
      val.w = src[reflect_i(g+3, 8192)];
    }
    *(float2*)&sVE[2*j4] = make_float2(val.x, val.z);
    *(float2*)&sVO[2*j4] = make_float2(val.y, val.w);
  }
  __syncthreads();

  {
    int base1m = 1040 * c - 32;
    int uh1 = (c < 3) ? 1072 : 1013;
    for (int u0 = 4 * tid; u0 < 1084; u0 += 1024) {
      float we[12], wo[12];
      ld3f4(we, &sVE[u0]); ld3f4(wo, &sVO[u0]);
      float lo4[4], hi4[4];
      #pragma unroll
      for (int d = 0; d < 4; ++d) {
        float alo = 0.f, ahi = 0.f;
        #pragma unroll
        for (int j = 0; j < 6; ++j) {
          float e = we[d+1+j], oo = wo[d+1+j];
          alo += e * rec_lo_c(2*j) + oo * rec_lo_c(2*j+1);
          ahi += e * rec_hi_c(2*j) + oo * rec_hi_c(2*j+1);
        }
        lo4[d] = alo; hi4[d] = ahi;
      }
      *(float2*)&sL1E[u0 >> 1] = make_float2(lo4[0], lo4[2]);
      *(float2*)&sL1O[u0 >> 1] = make_float2(lo4[1], lo4[3]);
      if (u0 >= 32 && u0 + 3 < uh1) {
        *(float4*)&hseq[base1m + u0] = make_float4(hi4[0], hi4[1], hi4[2], hi4[3]);
      } else {
        #pragma unroll
        for (int d = 0; d < 4; ++d) {
          int u = u0 + d;
          if (u >= 32 && u < uh1) hseq[base1m + u] = hi4[d];
        }
      }
    }
  }
  __syncthreads();
  if (c == 0) {
    for (int u = tid; u < 32; u += 256) {
      int j = 63 - u;
      float v = (j & 1) ? sL1O[j >> 1] : sL1E[j >> 1];
      if (u & 1) sL1O[u >> 1] = v; else sL1E[u >> 1] = v;
    }
  }
  if (c == 3) {
    for (int u = 1013 + tid; u < 1084; u += 256) {
      int j = 2025 - u;
      float v = (j & 1) ? sL1O[j >> 1] : sL1E[j >> 1];
      if (u & 1) sL1O[u >> 1] = v; else sL1E[u >> 1] = v;
    }
  }
  __syncthreads();

  {
    int base2m = 520 * c - 12;
    int uh2 = (c < 3) ? 532 : 508;
    for (int u0 = 4 * tid; u0 < 536; u0 += 1024) {
      float we[12], wo[12];
      ld3f4(we, &sL1E[u0 - 4]); ld3f4(wo, &sL1O[u0 - 4]);
      float lo4[4], hi4[4];
      #pragma unroll
      for (int d = 0; d < 4; ++d) {
        float alo = 0.f, ahi = 0.f;
        #pragma unroll
        for (int j = 0; j < 6; ++j) {
          float e = we[d+3+j], oo = wo[d+3+j];
          alo += e * rec_lo_c(2*j) + oo * rec_lo_c(2*j+1);
          ahi += e * rec_hi_c(2*j) + oo * rec_hi_c(2*j+1);
        }
        lo4[d] = alo; hi4[d] = ahi;
      }
      *(float2*)&sL2E[u0 >> 1] = make_float2(lo4[0], lo4[2]);
      *(float2*)&sL2O[u0 >> 1] = make_float2(lo4[1], lo4[3]);
      if (u0 >= 12 && u0 < uh2)
        *(float4*)&hseq[4104 + base2m + u0] = make_float4(hi4[0], hi4[1], hi4[2], hi4[3]);
    }
  }
  __syncthreads();
  if (c == 0) {
    for (int u = tid; u < 12; u += 256) {
      int j = 23 - u;
      float v = (j & 1) ? sL2O[j >> 1] : sL2E[j >> 1];
      if (u & 1) sL2O[u >> 1] = v; else sL2E[u >> 1] = v;
    }
  }
  if (c == 3) {
    for (int u = 508 + tid; u < 536; u += 256) {
      int j = 1015 - u;
      float v = (j & 1) ? sL2O[j >> 1] : sL2E[j >> 1];
      if (u & 1) sL2O[u >> 1] = v; else sL2E[u >> 1] = v;
    }
  }
  __syncthreads();

  for (int u0 = 4 * tid; u0 < 260; u0 += 1024) {
    float we[12], wo[12];
    ld3f4(we, &sL2E[u0]); ld3f4(wo, &sL2O[u0]);
    float lo4[4], hi4[4];
    #pragma unroll
    for (int d = 0; d < 4; ++d) {
      float alo = 0.f, ahi = 0.f;
      #pragma unroll
      for (int j = 0; j < 6; ++j) {
        float e = we[d+1+j], oo = wo[d+1+j];
        alo += e * rec_lo_c(2*j) + oo * rec_lo_c(2*j+1);
        ahi += e * rec_hi_c(2*j) + oo * rec_hi_c(2*j+1);
      }
      lo4[d] = alo; hi4[d] = ahi;
    }
    int m0 = 260 * c + u0;
    if (m0 + 3 < 1033) {
      *(float4*)&lo_f[(size_t)seq * LO_STR + m0] = make_float4(lo4[0], lo4[1], lo4[2], lo4[3]);
      *(float4*)&hseq[6160 + m0] = make_float4(hi4[0], hi4[1], hi4[2], hi4[3]);
    } else {
      #pragma unroll
      for (int d = 0; d < 4; ++d) {
        int m = m0 + d;
        if (m < 1033 && u0 + d < 260) {
          lo_f[(size_t)seq * LO_STR + m] = lo4[d];
          hseq[6160 + m] = hi4[d];
        }
      }
    }
  }
}

// ---------------------------------------------------------------- DWT small x4: 1033->...->42, 4 seqs/block (1 wave each)
__device__ __forceinline__ void dwt_lvl_v64(const float* in, int n, float* out, int outn, float* hg, int t64)
{
  for (int u0 = 4*t64; u0 < outn; u0 += 256) {
    bool fast = (u0 >= 8) && (2*u0 + 7 < n) && (u0 + 3 < outn);
    if (fast) {
      float w[20];
      ld5f4(w, &in[2*u0 - 12]);
      #pragma unroll
      for (int d = 0; d < 4; ++d) {
        float alo = 0.f, ahi = 0.f;
        #pragma unroll
        for (int k = 0; k < 12; ++k) {
          float x = w[2*d + 2 + k];
          alo += x * rec_lo_c(k); ahi += x * rec_hi_c(k);
        }
        out[u0+d] = alo; hg[u0+d] = ahi;
      }
    } else {
      for (int d = 0; d < 4; ++d) {
        if (u0 + d < outn) {
          float alo = 0.f, ahi = 0.f;
          #pragma unroll
          for (int k = 0; k < 12; ++k) {
            float x = in[reflect_i(2*(u0+d) + k - 10, n)];
            alo += x * rec_lo_c(k); ahi += x * rec_hi_c(k);
          }
          out[u0+d] = alo; hg[u0+d] = ahi;
        }
      }
    }
  }
  __syncthreads();
}

__global__ __launch_bounds__(256) void dwt_small(
    const float* __restrict__ lo_f, float* __restrict__ highs, float* __restrict__ yl)
{
  __shared__ alignas(16) float A[4][1040], Bb[4][528];
  int sub = threadIdx.x >> 6, t64 = threadIdx.x & 63;
  int seq = blockIdx.x * 4 + sub;
  const float* src = lo_f + (size_t)seq * LO_STR;
  float* hseq = highs + (size_t)seq * HTOT;
  float* As = A[sub];
  float* Bs = Bb[sub];
  for (int i = 4*t64; i < 1033; i += 256) {
    if (i + 3 < 1033) *(float4*)&As[i] = *(const float4*)&src[i];
    else { for (int d = 0; d < 4; ++d) if (i + d < 1033) As[i+d] = src[i+d]; }
  }
  __syncthreads();
  dwt_lvl_v64(As, 1033, Bs, 522, hseq + 7196, t64);
  dwt_lvl_v64(Bs, 522, As, 266, hseq + 7720, t64);
  dwt_lvl_v64(As, 266, Bs, 138, hseq + 7988, t64);
  dwt_lvl_v64(Bs, 138, As, 74,  hseq + 8128, t64);
  dwt_lvl_v64(As, 74,  Bs, 42,  hseq + 8204, t64);
  for (int m = t64; m < MODES; m += 64) yl[seq * MODES + m] = Bs[m];
}

// ---------------------------------------------------------------- IDWT small x4 + fused channel mix (serial, validated)
__device__ __forceinline__ void idwt_lvl4_64(const float* lo, const float* h, float* out, int outn, int t64)
{
  for (int u0 = 4*t64; u0 < outn; u0 += 256) {
    int q = u0 >> 1;
    float wl[8], wh[8];
    ld4f2(wl, &lo[q]); ld4f2(wh, &h[q]);
    float o4[4]; idwt4s<0>(wl, wh, o4);
    if (u0 + 3 < outn) *(float4*)&out[u0] = make_float4(o4[0], o4[1], o4[2], o4[3]);
    else { for (int d = 0; d < 4; ++d) if (u0 + d < outn) out[u0+d] = o4[d]; }
  }
  __syncthreads();
}

__global__ __launch_bounds__(256) void idwt_small(
    const float* __restrict__ yl_raw, const float* __restrict__ highs,
    const float* __restrict__ w1l, const float* __restrict__ w2l,
    float* __restrict__ lo_i)
{
  // per-sub bands: yl@0(48) yh@48(48) h74@96(80) h138@176(144) h266@320(272) h522@592(528)
  __shared__ alignas(16) float bands[4][1120], wa[4][272], wb[4][528];
  int sub = threadIdx.x >> 6, t64 = threadIdx.x & 63;
  int seq = blockIdx.x * 4 + sub;
  int b = seq >> 6, o = seq & 63;
  const float* hseq = highs + (size_t)seq * HTOT;
  float* bs = bands[sub];
  float* was = wa[sub];
  float* wbs = wb[sub];

  stage_band4_64(bs + 96,  hseq + 8128, 74, 80, t64);
  stage_band4_64(bs + 176, hseq + 7988, 138, 144, t64);
  stage_band4_64(bs + 320, hseq + 7720, 266, 272, t64);
  stage_band4_64(bs + 592, hseq + 7196, 522, 528, t64);

  if (t64 >= 42 && t64 < 48) { bs[t64] = 0.f; bs[48 + t64] = 0.f; }
  if (t64 < 42) {
    const float* yr = yl_raw + (size_t)b * 2688 + t64;               // + i*42
    const float* hh = highs + (size_t)(b * 64) * HTOT + 8204 + t64;  // + i*HTOT
    const float* wl = w1l + o * 42 + t64;                             // + i*2688
    const float* wh = w2l + o * 42 + t64;
    float accl = 0.f, acch = 0.f;
    #pragma unroll 4
    for (int i = 0; i < 64; ++i) {
      accl += yr[i * 42] * wl[i * 2688];
      acch += hh[(size_t)i * HTOT] * wh[i * 2688];
    }
    bs[t64] = accl; bs[48 + t64] = acch;
  }
  __syncthreads();

  idwt_lvl4_64(bs + 0,   bs + 48,  was, 74, t64);
  idwt_lvl4_64(was,      bs + 96,  wbs, 138, t64);
  idwt_lvl4_64(wbs,      bs + 176, was, 266, t64);
  idwt_lvl4_64(was,      bs + 320, wbs, 522, t64);

  for (int u0 = 4 * t64; u0 < 1033; u0 += 256) {
    int q = u0 >> 1;
    float wl[8], wh[8];
    ld4f2(wl, &wbs[q]); ld4f2(wh, &bs[592 + q]);
    float o4[4]; idwt4s<0>(wl, wh, o4);
    float* dst = lo_i + (size_t)seq * LO_STR + u0;
    if (u0 + 3 < 1033) *(float4*)&dst[0] = make_float4(o4[0], o4[1], o4[2], o4[3]);
    else { for (int d = 0; d < 4; ++d) if (u0 + d < 1033) dst[d] = o4[d]; }
  }
}

// ---------------------------------------------------------------- IDWT big: 1033->2056->4101->8192, 4 chunks/seq (round-9 validated)
__global__ __launch_bounds__(256) void idwt_big(
    const float* __restrict__ lo_i, const float* __restrict__ highs, float* __restrict__ x1)
{
  __shared__ alignas(16) float sL3[288], sH3[288], sL2[544], sH2[544], sL1[1048], sH1[1048];
  int seq = blockIdx.x >> 2, c = blockIdx.x & 3;
  const float* hseq = highs + (size_t)seq * HTOT;
  const float* l3   = lo_i + (size_t)seq * LO_STR;
  int g3 = 256*c - 4, g2 = 512*c - 4, g1 = 1024*c - 4;
  int t = threadIdx.x;

  stage_g(sL3, l3,          g3, 288, 1033);
  stage_g(sH3, hseq + 6160, g3, 288, 1033);
  stage_g(sH2, hseq + 4104, g2, 544, 2056);
  stage_g(sH1, hseq,        g1, 1048, 4101);
  __syncthreads();

  for (int u0 = 4 * t; u0 < 536; u0 += 1024) {
    int q = u0 >> 1;
    float wl[8], wh[8];
    ld4f2(wl, &sL3[q + 2]); ld4f2(wh, &sH3[q + 2]);
    float o4[4]; idwt4s<1>(wl, wh, o4);
    #pragma unroll
    for (int d = 0; d < 4; ++d) {
      int m = 512*c - 2 + u0 + d;
      o4[d] = (m >= 0 && m < 2056) ? o4[d] : 0.f;
    }
    *(float2*)&sL2[u0 + 2] = make_float2(o4[0], o4[1]);
    *(float2*)&sL2[u0 + 4] = make_float2(o4[2], o4[3]);
  }
  __syncthreads();

  for (int u0 = 4 * t; u0 < 1040; u0 += 1024) {
    int q = u0 >> 1;
    float wl[8], wh[8];
    ld4f2(wl, &sL2[q + 2]); ld4f2(wh, &sH2[q + 2]);
    float o4[4]; idwt4s<1>(wl, wh, o4);
    #pragma unroll
    for (int d = 0; d < 4; ++d) {
      int m = 1024*c - 2 + u0 + d;
      o4[d] = (m >= 0 && m < 4101) ? o4[d] : 0.f;
    }
    *(float2*)&sL1[u0 + 2] = make_float2(o4[0], o4[1]);
    *(float2*)&sL1[u0 + 4] = make_float2(o4[2], o4[3]);
  }
  __syncthreads();

  for (int u0 = 4 * t; u0 < 2048; u0 += 1024) {
    int q = u0 >> 1;
    float wl[8], wh[8];
    ld4f2(wl, &sL1[q + 4]); ld4f2(wh, &sH1[q + 4]);
    float o4[4]; idwt4s<0>(wl, wh, o4);
    *(float4*)&x1[(size_t)seq * S_LEN + 2048*c + u0] = make_float4(o4[0], o4[1], o4[2], o4[3]);
  }
}

// ---------------------------------------------------------------- layer pointwise via MFMA (layers 0-2)
__global__ __launch_bounds__(256) void pw_mfma(
    const float* __restrict__ x1, float* v,
    const u16* __restrict__ wcH, const u16* __restrict__ wcL,
    const float* __restrict__ cb)
{
  __shared__ u16 aH[64][64], aL[64][64];
  __shared__ u16 wH[64][64], wL[64][64];
  __shared__ float cbl[64];
  int b  = blockIdx.x >> 7;
  int s0 = (blockIdx.x & 127) << 6;
  int t  = threadIdx.x;

  {
    const v8s* srcH = (const v8s*)wcH;
    const v8s* srcL = (const v8s*)wcL;
    v8s* dstH = (v8s*)&wH[0][0];
    v8s* dstL = (v8s*)&wL[0][0];
    #pragma unroll
    for (int r = 0; r < 2; ++r) {
      dstH[t + 256 * r] = srcH[t + 256 * r];
      dstL[t + 256 * r] = srcL[t + 256 * r];
    }
  }
  if (t < 64) cbl[t] = cb[t];

  #pragma unroll
  for (int r = 0; r < 4; ++r) {
    int idx = t + 256 * r;
    int ch = idx >> 4, p4 = (idx & 15) << 2;
    float4 xv = *(const float4*)&v[((size_t)(b * 64 + ch)) * S_LEN + s0 + p4];
    u16 h0 = bf16_rn(xv.x); aH[p4+0][ch ^ (((p4+0)&7)<<3)] = h0; aL[p4+0][ch ^ (((p4+0)&7)<<3)] = bf16_rn(xv.x - bf16_to_f(h0));
    u16 h1 = bf16_rn(xv.y); aH[p4+1][ch ^ (((p4+1)&7)<<3)] = h1; aL[p4+1][ch ^ (((p4+1)&7)<<3)] = bf16_rn(xv.y - bf16_to_f(h1));
    u16 h2 = bf16_rn(xv.z); aH[p4+2][ch ^ (((p4+2)&7)<<3)] = h2; aL[p4+2][ch ^ (((p4+2)&7)<<3)] = bf16_rn(xv.z - bf16_to_f(h2));
    u16 h3 = bf16_rn(xv.w); aH[p4+3][ch ^ (((p4+3)&7)<<3)] = h3; aL[p4+3][ch ^ (((p4+3)&7)<<3)] = bf16_rn(xv.w - bf16_to_f(h3));
  }
  __syncthreads();

  int l = t & 63, wv_ = t >> 6;
  int pi = l & 15, kg = l >> 4;
  int pos = wv_ * 16 + pi;
  int swz = (pi & 7) << 3;

  v4f acc[4];
  #pragma unroll
  for (int i = 0; i < 4; ++i) acc[i] = v4f{0.f, 0.f, 0.f, 0.f};

  #pragma unroll
  for (int kt = 0; kt < 2; ++kt) {
    int ka = (kg * 8 + kt * 32) ^ swz;
    v8s ah = *(const v8s*)&aH[pos][ka];
    v8s al = *(const v8s*)&aL[pos][ka];
    #pragma unroll
    for (int ct = 0; ct < 4; ++ct) {
      int o = ct * 16 + pi;
      v8s bh = *(const v8s*)&wH[o][ka];
      v8s bl = *(const v8s*)&wL[o][ka];
      acc[ct] = __builtin_amdgcn_mfma_f32_16x16x32_bf16(ah, bh, acc[ct], 0, 0, 0);
      acc[ct] = __builtin_amdgcn_mfma_f32_16x16x32_bf16(ah, bl, acc[ct], 0, 0, 0);
      acc[ct] = __builtin_amdgcn_mfma_f32_16x16x32_bf16(al, bh, acc[ct], 0, 0, 0);
    }
  }

  #pragma unroll
  for (int ct = 0; ct < 4; ++ct) {
    int o = ct * 16 + pi;
    size_t base = ((size_t)(b * 64 + o)) * S_LEN + s0 + wv_ * 16 + kg * 4;
    float4 x4 = *(const float4*)&x1[base];
    float cbv = cbl[o];
    float y0 = gelu_f(acc[ct][0] + x4.x + cbv);
    float y1 = gelu_f(acc[ct][1] + x4.y + cbv);
    float y2 = gelu_f(acc[ct][2] + x4.z + cbv);
    float y3 = gelu_f(acc[ct][3] + x4.w + cbv);
    float4 y4 = make_float4(y0, y1, y2, y3);
    *(float4*)&v[base] = y4;
  }
}

// ---------------------------------------------------------------- fused final layer: pw (no gelu) + head, LDS time-multiplexed
// pool layout (u16): aH[0..4095] aL[4096..8191] | weights[8192..24575]
//   phase 1: cwH @8192 (4096), cwL @12288 (4096)
//   phase 2: fc1H @8192 (8192), fc1L @16384 (8192)  (restaged after pw MFMA)
__global__ __launch_bounds__(256) void pw_head_mfma(
    const float* __restrict__ x1, const float* __restrict__ v,
    const u16* __restrict__ wcH, const u16* __restrict__ wcL,
    const float* __restrict__ cb,
    const u16* __restrict__ whH, const u16* __restrict__ whL,
    const float* __restrict__ fc1b, const float* __restrict__ fc2w,
    const float* __restrict__ fc2b, float* __restrict__ out)
{
  __shared__ alignas(16) u16 pool[24576];   // 48 KB
  __shared__ float cbl[64], f1b[128], f2w[128];
  u16 (*aH)[64] = (u16(*)[64])(pool);
  u16 (*aL)[64] = (u16(*)[64])(pool + 4096);
  int b  = blockIdx.x >> 7;
  int s0 = (blockIdx.x & 127) << 6;
  int t  = threadIdx.x;

  {  // phase-1 weights: cw into pool[8192..16383]
    const v8s* srcH = (const v8s*)wcH;
    const v8s* srcL = (const v8s*)wcL;
    v8s* dstH = (v8s*)(pool + 8192);
    v8s* dstL = (v8s*)(pool + 12288);
    #pragma unroll
    for (int r = 0; r < 2; ++r) {
      dstH[t + 256 * r] = srcH[t + 256 * r];
      dstL[t + 256 * r] = srcL[t + 256 * r];
    }
  }
  if (t < 64) cbl[t] = cb[t];
  if (t < 128) { f1b[t] = fc1b[t]; f2w[t] = fc2w[t]; }

  #pragma unroll
  for (int r = 0; r < 4; ++r) {
    int idx = t + 256 * r;
    int ch = idx >> 4, p4 = (idx & 15) << 2;
    float4 xv = *(const float4*)&v[((size_t)(b * 64 + ch)) * S_LEN + s0 + p4];
    u16 h0 = bf16_rn(xv.x); aH[p4+0][ch ^ (((p4+0)&7)<<3)] = h0; aL[p4+0][ch ^ (((p4+0)&7)<<3)] = bf16_rn(xv.x - bf16_to_f(h0));
    u16 h1 = bf16_rn(xv.y); aH[p4+1][ch ^ (((p4+1)&7)<<3)] = h1; aL[p4+1][ch ^ (((p4+1)&7)<<3)] = bf16_rn(xv.y - bf16_to_f(h1));
    u16 h2 = bf16_rn(xv.z); aH[p4+2][ch ^ (((p4+2)&7)<<3)] = h2; aL[p4+2][ch ^ (((p4+2)&7)<<3)] = bf16_rn(xv.z - bf16_to_f(h2));
    u16 h3 = bf16_rn(xv.w); aH[p4+3][ch ^ (((p4+3)&7)<<3)] = h3; aL[p4+3][ch ^ (((p4+3)&7)<<3)] = bf16_rn(xv.w - bf16_to_f(h3));
  }
  __syncthreads();

  int l = t & 63, wv_ = t >> 6;
  int pi = l & 15, kg = l >> 4;
  int pos = wv_ * 16 + pi;
  int swz = (pi & 7) << 3;

  // ---- pw MFMA (cw mix, K=64)
  v4f acc[4];
  #pragma unroll
  for (int i = 0; i < 4; ++i) acc[i] = v4f{0.f, 0.f, 0.f, 0.f};
  #pragma unroll
  for (int kt = 0; kt < 2; ++kt) {
    int ka = (kg * 8 + kt * 32) ^ swz;
    v8s ah = *(const v8s*)&aH[pos][ka];
    v8s al = *(const v8s*)&aL[pos][ka];
    #pragma unroll
    for (int ct = 0; ct < 4; ++ct) {
      int o = ct * 16 + pi;
      v8s bh = *(const v8s*)&pool[8192  + o * 64 + ka];
      v8s bl = *(const v8s*)&pool[12288 + o * 64 + ka];
      acc[ct] = __builtin_amdgcn_mfma_f32_16x16x32_bf16(ah, bh, acc[ct], 0, 0, 0);
      acc[ct] = __builtin_amdgcn_mfma_f32_16x16x32_bf16(ah, bl, acc[ct], 0, 0, 0);
      acc[ct] = __builtin_amdgcn_mfma_f32_16x16x32_bf16(al, bh, acc[ct], 0, 0, 0);
    }
  }
  __syncthreads();   // all reads of aH/aL and cw region complete

  // ---- restage phase-2 weights: fc1 into pool[8192..24575] (cw region is dead)
  {
    const v8s* srcH = (const v8s*)whH;
    const v8s* srcL = (const v8s*)whL;
    v8s* dstH = (v8s*)(pool + 8192);
    v8s* dstL = (v8s*)(pool + 16384);
    #pragma unroll
    for (int r = 0; r < 4; ++r) {
      dstH[t + 256 * r] = srcH[t + 256 * r];
      dstL[t + 256 * r] = srcL[t + 256 * r];
    }
  }
  // ---- write y = acc + x1 + cb (no gelu, layer 3) back into aH/aL as split bf16
  #pragma unroll
  for (int ct = 0; ct < 4; ++ct) {
    int o = ct * 16 + pi;
    size_t base = ((size_t)(b * 64 + o)) * S_LEN + s0 + wv_ * 16 + kg * 4;
    float4 x4 = *(const float4*)&x1[base];
    float cbv = cbl[o];
    float y[4] = { acc[ct][0] + x4.x + cbv, acc[ct][1] + x4.y + cbv,
                   acc[ct][2] + x4.z + cbv, acc[ct][3] + x4.w + cbv };
    #pragma unroll
    for (int d = 0; d < 4; ++d) {
      int p = wv_ * 16 + kg * 4 + d;
      int cs = o ^ ((p & 7) << 3);
      u16 h = bf16_rn(y[d]);
      aH[p][cs] = h;
      aL[p][cs] = bf16_rn(y[d] - bf16_to_f(h));
    }
  }
  __syncthreads();

  // ---- head MFMA (fc1, K=64, 8 column tiles)
  v4f hacc[8];
  #pragma unroll
  for (int i = 0; i < 8; ++i) hacc[i] = v4f{0.f, 0.f, 0.f, 0.f};
  #pragma unroll
  for (int kt = 0; kt < 2; ++kt) {
    int ka = (kg * 8 + kt * 32) ^ swz;
    v8s ah = *(const v8s*)&aH[pos][ka];
    v8s al = *(const v8s*)&aL[pos][ka];
    #pragma unroll
    for (int ct = 0; ct < 8; ++ct) {
      int j = ct * 16 + pi;
      v8s bh = *(const v8s*)&pool[8192  + j * 64 + ka];
      v8s bl = *(const v8s*)&pool[16384 + j * 64 + ka];
      hacc[ct] = __builtin_amdgcn_mfma_f32_16x16x32_bf16(ah, bh, hacc[ct], 0, 0, 0);
      hacc[ct] = __builtin_amdgcn_mfma_f32_16x16x32_bf16(ah, bl, hacc[ct], 0, 0, 0);
      hacc[ct] = __builtin_amdgcn_mfma_f32_16x16x32_bf16(al, bh, hacc[ct], 0, 0, 0);
    }
  }

  float part[4] = {0.f, 0.f, 0.f, 0.f};
  #pragma unroll
  for (int ct = 0; ct < 8; ++ct) {
    int j = ct * 16 + pi;
    float bias = f1b[j], f2 = f2w[j];
    #pragma unroll
    for (int r = 0; r < 4; ++r) {
      float d = hacc[ct][r] + bias;
      part[r] += f2 * gelu_f(d);
    }
  }
  #pragma unroll
  for (int r = 0; r < 4; ++r) {
    part[r] += __shfl_xor(part[r], 1, 16);
    part[r] += __shfl_xor(part[r], 2, 16);
    part[r] += __shfl_xor(part[r], 4, 16);
    part[r] += __shfl_xor(part[r], 8, 16);
  }
  if (pi == 0) {
    float b2 = fc2b[0];
    float4 o4 = make_float4(part[0] + b2, part[1] + b2, part[2] + b2, part[3] + b2);
    *(float4*)&out[(size_t)b * S_LEN + s0 + wv_ * 16 + kg * 4] = o4;
  }
}

// ----------------------------------------------------------------
extern "C" void kernel_launch(void* const* d_in, const int* in_sizes, int n_in,
                              void* d_out, int out_size, void* d_ws, size_t ws_size,
                              hipStream_t stream) {
  const float* x    = (const float*)d_in[0];
  const float* fc0w = (const float*)d_in[1];
  const float* fc0b = (const float*)d_in[2];
  const float* w1   = (const float*)d_in[3];
  const float* w2   = (const float*)d_in[4];
  const float* cw   = (const float*)d_in[5];
  const float* cb   = (const float*)d_in[6];
  const float* fc1w = (const float*)d_in[7];
  const float* fc1b = (const float*)d_in[8];
  const float* fc2w = (const float*)d_in[9];
  const float* fc2b = (const float*)d_in[10];
  float* out = (float*)d_out;

  float* ws     = (float*)d_ws;
  float* v      = ws;
  float* x1     = v      + (size_t)BC * S_LEN;
  float* highs  = x1     + (size_t)BC * S_LEN;
  float* yl_raw = highs  + (size_t)BC * HTOT;
  float* lo_f   = yl_raw + (size_t)BC * MODES;
  float* lo_i   = lo_f   + (size_t)BC * LO_STR;
  u16*   whH    = (u16*)(lo_i + (size_t)BC * LO_STR);
  u16*   whL    = whH + 8192;
  u16*   wcH    = whL + 8192;
  u16*   wcL    = wcH + 16384;
  size_t needed = (size_t)((char*)(wcL + 16384) - (char*)ws);
  if (ws_size < needed) return;

  prep_split<<<96, 256, 0, stream>>>(fc1w, cw, whH, whL, wcH, wcL);
  fc0_kernel<<<16384, 256, 0, stream>>>(x, fc0w, fc0b, v);

  for (int i = 0; i < 4; ++i) {
    const float* w1l = w1 + (size_t)i * 64 * 64 * MODES;
    const float* w2l = w2 + (size_t)i * 64 * 64 * MODES;
    dwt_big<<<BC * 4, 256, 0, stream>>>(v, highs, lo_f);
    dwt_small<<<BC / 4, 256, 0, stream>>>(lo_f, highs, yl_raw);
    idwt_small<<<BC / 4, 256, 0, stream>>>(yl_raw, highs, w1l, w2l, lo_i);
    idwt_big<<<BC * 4, 256, 0, stream>>>(lo_i, highs, x1);
    if (i < 3) {
      pw_mfma<<<4096, 256, 0, stream>>>(x1, v, wcH + i * 4096, wcL + i * 4096, cb + i * 64);
    } else {
      pw_head_mfma<<<4096, 256, 0, stream>>>(x1, v, wcH + i * 4096, wcL + i * 4096, cb + i * 64,
                                             whH, whL, fc1b, fc2w, fc2b, out);
    }
  }
}

// Round 18
// 565.844 us; speedup vs baseline: 1.1533x; 1.0099x over previous
//
#include <hip/hip_runtime.h>
#include <cmath>

#define BC 2048          // B*W sequences
#define S_LEN 8192
#define MODES 42
// padded pyramid: L1@0(4101) L2@4104(2056) L3@6160(1033) L4@7196(522)
//                 L5@7720(266) L6@7988(138) L7@8128(74) L8@8204(42)
#define HTOT 8248
#define LO_STR 1036      // padded stride for the 1033-long lo buffers

static constexpr float C_LO[12] = {
  0.11154074335008017f, 0.4946238903983854f, 0.7511339080215775f,
  0.3152503517092432f, -0.22626469396516913f, -0.12976686756709563f,
  0.09750160558707936f, 0.02752286553001629f, -0.031582039318031156f,
  0.0005538422009938016f, 0.004777257511010651f, -0.00107730108499558f };

__device__ __forceinline__ float rec_lo_c(int k){ return C_LO[k]; }
__device__ __forceinline__ float rec_hi_c(int k){ float v = C_LO[11-k]; return (k&1)? -v : v; }
__device__ __forceinline__ float dec_lo_c(int k){ return C_LO[11-k]; }
__device__ __forceinline__ float dec_hi_c(int k){ float v = C_LO[k];    return (k&1)?  v : -v; }

// branchless erf (Abramowitz-Stegun 7.1.26, |err|<=1.5e-7)
__device__ __forceinline__ float erf_fast(float x){
  float ax = fabsf(x);
  float t  = __fdividef(1.0f, 1.0f + 0.3275911f * ax);
  float p  = ((((1.061405429f * t - 1.453152027f) * t) + 1.421413741f) * t - 0.284496736f) * t + 0.254829592f;
  float y  = 1.0f - p * t * __expf(-ax * ax);
  return copysignf(y, x);
}
__device__ __forceinline__ float gelu_f(float x){
  return 0.5f * x * (1.0f + erf_fast(x * 0.70710678118654752440f));
}

__device__ __forceinline__ int reflect_i(int t, int n){
  t = (t < 0) ? (-1 - t) : t;
  t = (t >= n) ? (2 * n - 1 - t) : t;
  return t;
}

__device__ __forceinline__ unsigned short bf16_rn(float x){
  unsigned int b = __float_as_uint(x);
  b += 0x7FFF + ((b >> 16) & 1);
  return (unsigned short)(b >> 16);
}
__device__ __forceinline__ float bf16_to_f(unsigned short h){
  return __uint_as_float(((unsigned int)h) << 16);
}

typedef short  v8s __attribute__((ext_vector_type(8)));
typedef float  v4f __attribute__((ext_vector_type(4)));
typedef unsigned short u16;

__device__ __forceinline__ void ld3f4(float* w, const float* s){
  *(float4*)&w[0] = *(const float4*)&s[0];
  *(float4*)&w[4] = *(const float4*)&s[4];
  *(float4*)&w[8] = *(const float4*)&s[8];
}
__device__ __forceinline__ void ld5f4(float* w, const float* s){
  *(float4*)&w[0]  = *(const float4*)&s[0];
  *(float4*)&w[4]  = *(const float4*)&s[4];
  *(float4*)&w[8]  = *(const float4*)&s[8];
  *(float4*)&w[12] = *(const float4*)&s[12];
  *(float4*)&w[16] = *(const float4*)&s[16];
}
__device__ __forceinline__ void ld4f2(float* w, const float* s){
  *(float2*)&w[0] = *(const float2*)&s[0];
  *(float2*)&w[2] = *(const float2*)&s[2];
  *(float2*)&w[4] = *(const float2*)&s[4];
  *(float2*)&w[6] = *(const float2*)&s[6];
}

// zero-pad staging: dst[j] = (0<=g0+j<n) ? src[g0+j] : 0 ; g0%4==0, cnt%4==0
__device__ __forceinline__ void stage_g(float* dst, const float* src, int g0, int cnt, int n){
  for (int j4 = threadIdx.x; j4 < (cnt >> 2); j4 += 256) {
    int g = g0 + 4 * j4;
    float4 val;
    if (g >= 0 && g + 3 < n) val = *(const float4*)&src[g];
    else {
      val.x = (g   >= 0 && g   < n) ? src[g]   : 0.f;
      val.y = (g+1 >= 0 && g+1 < n) ? src[g+1] : 0.f;
      val.z = (g+2 >= 0 && g+2 < n) ? src[g+2] : 0.f;
      val.w = (g+3 >= 0 && g+3 < n) ? src[g+3] : 0.f;
    }
    *(float4*)&dst[4*j4] = val;
  }
}

// per-sub (64-thread) band staging
__device__ __forceinline__ void stage_band4_64(float* dst, const float* src, int len, int alloc, int t64){
  for (int i4 = t64; i4 < (alloc >> 2); i4 += 64) {
    int i = 4 * i4;
    float4 v;
    if (i + 3 < len) v = *(const float4*)&src[i];
    else {
      v.x = (i   < len) ? src[i]   : 0.f;
      v.y = (i+1 < len) ? src[i+1] : 0.f;
      v.z = (i+2 < len) ? src[i+2] : 0.f;
      v.w = (i+3 < len) ? src[i+3] : 0.f;
    }
    *(float4*)&dst[i] = v;
  }
}

// 4 IDWT outputs m=u0..u0+3 from windows wl/wh[8]; tap base SH + (d>>1)
template<int SH>
__device__ __forceinline__ void idwt4s(const float* wl, const float* wh, float* o4){
  #pragma unroll
  for (int d = 0; d < 4; ++d) {
    const int q = SH + (d >> 1);
    float acc = 0.f;
    if (d & 1) {
      #pragma unroll
      for (int i = 0; i < 6; ++i) acc += wl[q+i]*dec_lo_c(2*i)   + wh[q+i]*dec_hi_c(2*i);
    } else {
      #pragma unroll
      for (int i = 0; i < 6; ++i) acc += wl[q+i]*dec_lo_c(2*i+1) + wh[q+i]*dec_hi_c(2*i+1);
    }
    o4[d] = acc;
  }
}

// ---------------------------------------------------------------- prep: split weights to hi/lo bf16 in swizzled layout
__global__ __launch_bounds__(256) void prep_split(
    const float* __restrict__ fc1w, const float* __restrict__ cw,
    u16* __restrict__ whH, u16* __restrict__ whL,
    u16* __restrict__ wcH, u16* __restrict__ wcL)
{
  int i = blockIdx.x * 256 + threadIdx.x;
  if (i < 8192) {
    int c = i >> 7, j = i & 127;
    float wv = fc1w[i];
    u16 h = bf16_rn(wv);
    float lo = wv - bf16_to_f(h);
    int cs = c ^ ((j & 7) << 3);
    whH[j * 64 + cs] = h; whL[j * 64 + cs] = bf16_rn(lo);
  }
  int k = i - 8192;
  if (k >= 0 && k < 16384) {
    int l = k >> 12, r = k & 4095;
    int c = r >> 6, o = r & 63;
    float wv = cw[k];
    u16 h = bf16_rn(wv);
    float lo = wv - bf16_to_f(h);
    int cs = c ^ ((o & 7) << 3);
    wcH[l * 4096 + o * 64 + cs] = h; wcL[l * 4096 + o * 64 + cs] = bf16_rn(lo);
  }
}

// ---------------------------------------------------------------- fc0 (coalesced float4)
__global__ __launch_bounds__(256) void fc0_kernel(
    const float* __restrict__ x, const float* __restrict__ w,
    const float* __restrict__ bias, float* __restrict__ v)
{
  int p = blockIdx.x * 256 + threadIdx.x;     // (b, c, s4)
  int s4 = (p & 2047) << 2;
  int c  = (p >> 11) & 63;
  int b  = p >> 17;
  float4 xv = *(const float4*)&x[b * S_LEN + s4];
  float w0 = w[c], w1v = w[64 + c], bc = bias[c];
  const float inv = 1.0f / 8191.0f;
  float4 o;
  o.x = xv.x * w0 + (float)(s4    ) * inv * w1v + bc;
  o.y = xv.y * w0 + (float)(s4 + 1) * inv * w1v + bc;
  o.z = xv.z * w0 + (float)(s4 + 2) * inv * w1v + bc;
  o.w = xv.w * w0 + (float)(s4 + 3) * inv * w1v + bc;
  *(float4*)&v[((size_t)(b * 64 + c)) * S_LEN + s4] = o;
}

// ---------------------------------------------------------------- DWT big: 8192->4101->2056->1033, 4 chunks/seq
__global__ __launch_bounds__(256) void dwt_big(
    const float* __restrict__ vin, float* __restrict__ highs, float* __restrict__ lo_f)
{
  __shared__ alignas(16) float sVE[1096], sVO[1096];
  __shared__ alignas(16) float sL1Eb[548], sL1Ob[548];   // +4 front pad
  __shared__ alignas(16) float sL2E[276], sL2O[276];
  float* sL1E = sL1Eb + 4;
  float* sL1O = sL1Ob + 4;

  int seq = blockIdx.x >> 2, c = blockIdx.x & 3;
  const float* src = vin + (size_t)seq * S_LEN;
  float* hseq = highs + (size_t)seq * HTOT;
  int tid = threadIdx.x;

  int g0 = 2080 * c - 76;
  for (int j4 = tid; j4 < 545; j4 += 256) {
    int g = g0 + 4 * j4;
    float4 val;
    if (g >= 0 && g + 3 < 8192) val = *(const float4*)&src[g];
    else {
      val.x = src[reflect_i(g,   8192)];
      val.y = src[reflect_i(g+1, 8192)];
      val.z = src[reflect_i(g+2, 8192)];
      val.w = src[reflect_i(g+3, 8192)];
    }
    *(float2*)&sVE[2*j4] = make_float2(val.x, val.z);
    *(float2*)&sVO[2*j4] = make_float2(val.y, val.w);
  }
  __syncthreads();

  {
    int base1m = 1040 * c - 32;
    int uh1 = (c < 3) ? 1072 : 1013;
    for (int u0 = 4 * tid; u0 < 1084; u0 += 1024) {
      float we[12], wo[12];
      ld3f4(we, &sVE[u0]); ld3f4(wo, &sVO[u0]);
      float lo4[4], hi4[4];
      #pragma unroll
      for (int d = 0; d < 4; ++d) {
        float alo = 0.f, ahi = 0.f;
        #pragma unroll
        for (int j = 0; j < 6; ++j) {
          float e = we[d+1+j], oo = wo[d+1+j];
          alo += e * rec_lo_c(2*j) + oo * rec_lo_c(2*j+1);
          ahi += e * rec_hi_c(2*j) + oo * rec_hi_c(2*j+1);
        }
        lo4[d] = alo; hi4[d] = ahi;
      }
      *(float2*)&sL1E[u0 >> 1] = make_float2(lo4[0], lo4[2]);
      *(float2*)&sL1O[u0 >> 1] = make_float2(lo4[1], lo4[3]);
      if (u0 >= 32 && u0 + 3 < uh1) {
        *(float4*)&hseq[base1m + u0] = make_float4(hi4[0], hi4[1], hi4[2], hi4[3]);
      } else {
        #pragma unroll
        for (int d = 0; d < 4; ++d) {
          int u = u0 + d;
          if (u >= 32 && u < uh1) hseq[base1m + u] = hi4[d];
        }
      }
    }
  }
  __syncthreads();
  if (c == 0) {
    for (int u = tid; u < 32; u += 256) {
      int j = 63 - u;
      float v = (j & 1) ? sL1O[j >> 1] : sL1E[j >> 1];
      if (u & 1) sL1O[u >> 1] = v; else sL1E[u >> 1] = v;
    }
  }
  if (c == 3) {
    for (int u = 1013 + tid; u < 1084; u += 256) {
      int j = 2025 - u;
      float v = (j & 1) ? sL1O[j >> 1] : sL1E[j >> 1];
      if (u & 1) sL1O[u >> 1] = v; else sL1E[u >> 1] = v;
    }
  }
  __syncthreads();

  {
    int base2m = 520 * c - 12;
    int uh2 = (c < 3) ? 532 : 508;
    for (int u0 = 4 * tid; u0 < 536; u0 += 1024) {
      float we[12], wo[12];
      ld3f4(we, &sL1E[u0 - 4]); ld3f4(wo, &sL1O[u0 - 4]);
      float lo4[4], hi4[4];
      #pragma unroll
      for (int d = 0; d < 4; ++d) {
        float alo = 0.f, ahi = 0.f;
        #pragma unroll
        for (int j = 0; j < 6; ++j) {
          float e = we[d+3+j], oo = wo[d+3+j];
          alo += e * rec_lo_c(2*j) + oo * rec_lo_c(2*j+1);
          ahi += e * rec_hi_c(2*j) + oo * rec_hi_c(2*j+1);
        }
        lo4[d] = alo; hi4[d] = ahi;
      }
      *(float2*)&sL2E[u0 >> 1] = make_float2(lo4[0], lo4[2]);
      *(float2*)&sL2O[u0 >> 1] = make_float2(lo4[1], lo4[3]);
      if (u0 >= 12 && u0 < uh2)
        *(float4*)&hseq[4104 + base2m + u0] = make_float4(hi4[0], hi4[1], hi4[2], hi4[3]);
    }
  }
  __syncthreads();
  if (c == 0) {
    for (int u = tid; u < 12; u += 256) {
      int j = 23 - u;
      float v = (j & 1) ? sL2O[j >> 1] : sL2E[j >> 1];
      if (u & 1) sL2O[u >> 1] = v; else sL2E[u >> 1] = v;
    }
  }
  if (c == 3) {
    for (int u = 508 + tid; u < 536; u += 256) {
      int j = 1015 - u;
      float v = (j & 1) ? sL2O[j >> 1] : sL2E[j >> 1];
      if (u & 1) sL2O[u >> 1] = v; else sL2E[u >> 1] = v;
    }
  }
  __syncthreads();

  for (int u0 = 4 * tid; u0 < 260; u0 += 1024) {
    float we[12], wo[12];
    ld3f4(we, &sL2E[u0]); ld3f4(wo, &sL2O[u0]);
    float lo4[4], hi4[4];
    #pragma unroll
    for (int d = 0; d < 4; ++d) {
      float alo = 0.f, ahi = 0.f;
      #pragma unroll
      for (int j = 0; j < 6; ++j) {
        float e = we[d+1+j], oo = wo[d+1+j];
        alo += e * rec_lo_c(2*j) + oo * rec_lo_c(2*j+1);
        ahi += e * rec_hi_c(2*j) + oo * rec_hi_c(2*j+1);
      }
      lo4[d] = alo; hi4[d] = ahi;
    }
    int m0 = 260 * c + u0;
    if (m0 + 3 < 1033) {
      *(float4*)&lo_f[(size_t)seq * LO_STR + m0] = make_float4(lo4[0], lo4[1], lo4[2], lo4[3]);
      *(float4*)&hseq[6160 + m0] = make_float4(hi4[0], hi4[1], hi4[2], hi4[3]);
    } else {
      #pragma unroll
      for (int d = 0; d < 4; ++d) {
        int m = m0 + d;
        if (m < 1033 && u0 + d < 260) {
          lo_f[(size_t)seq * LO_STR + m] = lo4[d];
          hseq[6160 + m] = hi4[d];
        }
      }
    }
  }
}

// ---------------------------------------------------------------- DWT small x4: 1033->...->42, 4 seqs/block (1 wave each)
__device__ __forceinline__ void dwt_lvl_v64(const float* in, int n, float* out, int outn, float* hg, int t64)
{
  for (int u0 = 4*t64; u0 < outn; u0 += 256) {
    bool fast = (u0 >= 8) && (2*u0 + 7 < n) && (u0 + 3 < outn);
    if (fast) {
      float w[20];
      ld5f4(w, &in[2*u0 - 12]);
      #pragma unroll
      for (int d = 0; d < 4; ++d) {
        float alo = 0.f, ahi = 0.f;
        #pragma unroll
        for (int k = 0; k < 12; ++k) {
          float x = w[2*d + 2 + k];
          alo += x * rec_lo_c(k); ahi += x * rec_hi_c(k);
        }
        out[u0+d] = alo; hg[u0+d] = ahi;
      }
    } else {
      for (int d = 0; d < 4; ++d) {
        if (u0 + d < outn) {
          float alo = 0.f, ahi = 0.f;
          #pragma unroll
          for (int k = 0; k < 12; ++k) {
            float x = in[reflect_i(2*(u0+d) + k - 10, n)];
            alo += x * rec_lo_c(k); ahi += x * rec_hi_c(k);
          }
          out[u0+d] = alo; hg[u0+d] = ahi;
        }
      }
    }
  }
  __syncthreads();
}

__global__ __launch_bounds__(256) void dwt_small(
    const float* __restrict__ lo_f, float* __restrict__ highs, float* __restrict__ yl)
{
  __shared__ alignas(16) float A[4][1040], Bb[4][528];
  int sub = threadIdx.x >> 6, t64 = threadIdx.x & 63;
  int seq = blockIdx.x * 4 + sub;
  const float* src = lo_f + (size_t)seq * LO_STR;
  float* hseq = highs + (size_t)seq * HTOT;
  float* As = A[sub];
  float* Bs = Bb[sub];
  for (int i = 4*t64; i < 1033; i += 256) {
    if (i + 3 < 1033) *(float4*)&As[i] = *(const float4*)&src[i];
    else { for (int d = 0; d < 4; ++d) if (i + d < 1033) As[i+d] = src[i+d]; }
  }
  __syncthreads();
  dwt_lvl_v64(As, 1033, Bs, 522, hseq + 7196, t64);
  dwt_lvl_v64(Bs, 522, As, 266, hseq + 7720, t64);
  dwt_lvl_v64(As, 266, Bs, 138, hseq + 7988, t64);
  dwt_lvl_v64(Bs, 138, As, 74,  hseq + 8128, t64);
  dwt_lvl_v64(As, 74,  Bs, 42,  hseq + 8204, t64);
  for (int m = t64; m < MODES; m += 64) yl[seq * MODES + m] = Bs[m];
}

// ---------------------------------------------------------------- IDWT small x4 + fused channel mix (serial, validated)
__device__ __forceinline__ void idwt_lvl4_64(const float* lo, const float* h, float* out, int outn, int t64)
{
  for (int u0 = 4*t64; u0 < outn; u0 += 256) {
    int q = u0 >> 1;
    float wl[8], wh[8];
    ld4f2(wl, &lo[q]); ld4f2(wh, &h[q]);
    float o4[4]; idwt4s<0>(wl, wh, o4);
    if (u0 + 3 < outn) *(float4*)&out[u0] = make_float4(o4[0], o4[1], o4[2], o4[3]);
    else { for (int d = 0; d < 4; ++d) if (u0 + d < outn) out[u0+d] = o4[d]; }
  }
  __syncthreads();
}

__global__ __launch_bounds__(256) void idwt_small(
    const float* __restrict__ yl_raw, const float* __restrict__ highs,
    const float* __restrict__ w1l, const float* __restrict__ w2l,
    float* __restrict__ lo_i)
{
  // per-sub bands: yl@0(48) yh@48(48) h74@96(80) h138@176(144) h266@320(272) h522@592(528)
  __shared__ alignas(16) float bands[4][1120], wa[4][272], wb[4][528];
  int sub = threadIdx.x >> 6, t64 = threadIdx.x & 63;
  int seq = blockIdx.x * 4 + sub;
  int b = seq >> 6, o = seq & 63;
  const float* hseq = highs + (size_t)seq * HTOT;
  float* bs = bands[sub];
  float* was = wa[sub];
  float* wbs = wb[sub];

  stage_band4_64(bs + 96,  hseq + 8128, 74, 80, t64);
  stage_band4_64(bs + 176, hseq + 7988, 138, 144, t64);
  stage_band4_64(bs + 320, hseq + 7720, 266, 272, t64);
  stage_band4_64(bs + 592, hseq + 7196, 522, 528, t64);

  if (t64 >= 42 && t64 < 48) { bs[t64] = 0.f; bs[48 + t64] = 0.f; }
  if (t64 < 42) {
    const float* yr = yl_raw + (size_t)b * 2688 + t64;               // + i*42
    const float* hh = highs + (size_t)(b * 64) * HTOT + 8204 + t64;  // + i*HTOT
    const float* wl = w1l + o * 42 + t64;                             // + i*2688
    const float* wh = w2l + o * 42 + t64;
    float accl = 0.f, acch = 0.f;
    #pragma unroll 4
    for (int i = 0; i < 64; ++i) {
      accl += yr[i * 42] * wl[i * 2688];
      acch += hh[(size_t)i * HTOT] * wh[i * 2688];
    }
    bs[t64] = accl; bs[48 + t64] = acch;
  }
  __syncthreads();

  idwt_lvl4_64(bs + 0,   bs + 48,  was, 74, t64);
  idwt_lvl4_64(was,      bs + 96,  wbs, 138, t64);
  idwt_lvl4_64(wbs,      bs + 176, was, 266, t64);
  idwt_lvl4_64(was,      bs + 320, wbs, 522, t64);

  for (int u0 = 4 * t64; u0 < 1033; u0 += 256) {
    int q = u0 >> 1;
    float wl[8], wh[8];
    ld4f2(wl, &wbs[q]); ld4f2(wh, &bs[592 + q]);
    float o4[4]; idwt4s<0>(wl, wh, o4);
    float* dst = lo_i + (size_t)seq * LO_STR + u0;
    if (u0 + 3 < 1033) *(float4*)&dst[0] = make_float4(o4[0], o4[1], o4[2], o4[3]);
    else { for (int d = 0; d < 4; ++d) if (u0 + d < 1033) dst[d] = o4[d]; }
  }
}

// ---------------------------------------------------------------- IDWT big: 1033->2056->4101->8192, 4 chunks/seq (round-9 validated)
__global__ __launch_bounds__(256) void idwt_big(
    const float* __restrict__ lo_i, const float* __restrict__ highs, float* __restrict__ x1)
{
  __shared__ alignas(16) float sL3[288], sH3[288], sL2[544], sH2[544], sL1[1048], sH1[1048];
  int seq = blockIdx.x >> 2, c = blockIdx.x & 3;
  const float* hseq = highs + (size_t)seq * HTOT;
  const float* l3   = lo_i + (size_t)seq * LO_STR;
  int g3 = 256*c - 4, g2 = 512*c - 4, g1 = 1024*c - 4;
  int t = threadIdx.x;

  stage_g(sL3, l3,          g3, 288, 1033);
  stage_g(sH3, hseq + 6160, g3, 288, 1033);
  stage_g(sH2, hseq + 4104, g2, 544, 2056);
  stage_g(sH1, hseq,        g1, 1048, 4101);
  __syncthreads();

  for (int u0 = 4 * t; u0 < 536; u0 += 1024) {
    int q = u0 >> 1;
    float wl[8], wh[8];
    ld4f2(wl, &sL3[q + 2]); ld4f2(wh, &sH3[q + 2]);
    float o4[4]; idwt4s<1>(wl, wh, o4);
    #pragma unroll
    for (int d = 0; d < 4; ++d) {
      int m = 512*c - 2 + u0 + d;
      o4[d] = (m >= 0 && m < 2056) ? o4[d] : 0.f;
    }
    *(float2*)&sL2[u0 + 2] = make_float2(o4[0], o4[1]);
    *(float2*)&sL2[u0 + 4] = make_float2(o4[2], o4[3]);
  }
  __syncthreads();

  for (int u0 = 4 * t; u0 < 1040; u0 += 1024) {
    int q = u0 >> 1;
    float wl[8], wh[8];
    ld4f2(wl, &sL2[q + 2]); ld4f2(wh, &sH2[q + 2]);
    float o4[4]; idwt4s<1>(wl, wh, o4);
    #pragma unroll
    for (int d = 0; d < 4; ++d) {
      int m = 1024*c - 2 + u0 + d;
      o4[d] = (m >= 0 && m < 4101) ? o4[d] : 0.f;
    }
    *(float2*)&sL1[u0 + 2] = make_float2(o4[0], o4[1]);
    *(float2*)&sL1[u0 + 4] = make_float2(o4[2], o4[3]);
  }
  __syncthreads();

  for (int u0 = 4 * t; u0 < 2048; u0 += 1024) {
    int q = u0 >> 1;
    float wl[8], wh[8];
    ld4f2(wl, &sL1[q + 4]); ld4f2(wh, &sH1[q + 4]);
    float o4[4]; idwt4s<0>(wl, wh, o4);
    *(float4*)&x1[(size_t)seq * S_LEN + 2048*c + u0] = make_float4(o4[0], o4[1], o4[2], o4[3]);
  }
}

// ---------------------------------------------------------------- layer pointwise via MFMA (layers 0-2)
__global__ __launch_bounds__(256) void pw_mfma(
    const float* __restrict__ x1, float* v,
    const u16* __restrict__ wcH, const u16* __restrict__ wcL,
    const float* __restrict__ cb)
{
  __shared__ u16 aH[64][64], aL[64][64];
  __shared__ u16 wH[64][64], wL[64][64];
  __shared__ float cbl[64];
  int b  = blockIdx.x >> 7;
  int s0 = (blockIdx.x & 127) << 6;
  int t  = threadIdx.x;

  {
    const v8s* srcH = (const v8s*)wcH;
    const v8s* srcL = (const v8s*)wcL;
    v8s* dstH = (v8s*)&wH[0][0];
    v8s* dstL = (v8s*)&wL[0][0];
    #pragma unroll
    for (int r = 0; r < 2; ++r) {
      dstH[t + 256 * r] = srcH[t + 256 * r];
      dstL[t + 256 * r] = srcL[t + 256 * r];
    }
  }
  if (t < 64) cbl[t] = cb[t];

  #pragma unroll
  for (int r = 0; r < 4; ++r) {
    int idx = t + 256 * r;
    int ch = idx >> 4, p4 = (idx & 15) << 2;
    float4 xv = *(const float4*)&v[((size_t)(b * 64 + ch)) * S_LEN + s0 + p4];
    u16 h0 = bf16_rn(xv.x); aH[p4+0][ch ^ (((p4+0)&7)<<3)] = h0; aL[p4+0][ch ^ (((p4+0)&7)<<3)] = bf16_rn(xv.x - bf16_to_f(h0));
    u16 h1 = bf16_rn(xv.y); aH[p4+1][ch ^ (((p4+1)&7)<<3)] = h1; aL[p4+1][ch ^ (((p4+1)&7)<<3)] = bf16_rn(xv.y - bf16_to_f(h1));
    u16 h2 = bf16_rn(xv.z); aH[p4+2][ch ^ (((p4+2)&7)<<3)] = h2; aL[p4+2][ch ^ (((p4+2)&7)<<3)] = bf16_rn(xv.z - bf16_to_f(h2));
    u16 h3 = bf16_rn(xv.w); aH[p4+3][ch ^ (((p4+3)&7)<<3)] = h3; aL[p4+3][ch ^ (((p4+3)&7)<<3)] = bf16_rn(xv.w - bf16_to_f(h3));
  }
  __syncthreads();

  int l = t & 63, wv_ = t >> 6;
  int pi = l & 15, kg = l >> 4;
  int pos = wv_ * 16 + pi;
  int swz = (pi & 7) << 3;

  v4f acc[4];
  #pragma unroll
  for (int i = 0; i < 4; ++i) acc[i] = v4f{0.f, 0.f, 0.f, 0.f};

  #pragma unroll
  for (int kt = 0; kt < 2; ++kt) {
    int ka = (kg * 8 + kt * 32) ^ swz;
    v8s ah = *(const v8s*)&aH[pos][ka];
    v8s al = *(const v8s*)&aL[pos][ka];
    #pragma unroll
    for (int ct = 0; ct < 4; ++ct) {
      int o = ct * 16 + pi;
      v8s bh = *(const v8s*)&wH[o][ka];
      v8s bl = *(const v8s*)&wL[o][ka];
      acc[ct] = __builtin_amdgcn_mfma_f32_16x16x32_bf16(ah, bh, acc[ct], 0, 0, 0);
      acc[ct] = __builtin_amdgcn_mfma_f32_16x16x32_bf16(ah, bl, acc[ct], 0, 0, 0);
      acc[ct] = __builtin_amdgcn_mfma_f32_16x16x32_bf16(al, bh, acc[ct], 0, 0, 0);
    }
  }

  #pragma unroll
  for (int ct = 0; ct < 4; ++ct) {
    int o = ct * 16 + pi;
    size_t base = ((size_t)(b * 64 + o)) * S_LEN + s0 + wv_ * 16 + kg * 4;
    float4 x4 = *(const float4*)&x1[base];
    float cbv = cbl[o];
    float y0 = gelu_f(acc[ct][0] + x4.x + cbv);
    float y1 = gelu_f(acc[ct][1] + x4.y + cbv);
    float y2 = gelu_f(acc[ct][2] + x4.z + cbv);
    float y3 = gelu_f(acc[ct][3] + x4.w + cbv);
    float4 y4 = make_float4(y0, y1, y2, y3);
    *(float4*)&v[base] = y4;
  }
}

// ---------------------------------------------------------------- fused final layer: pw (no gelu) + head, LDS double-multiplexed
// pool layout (u16): aH[0..4095] aL[4096..8191] | weights[8192..16383] (16 KB window)
//   phase 1 : cwH @8192 (4096), cwL @12288 (4096)
//   phase 2a: fc1H[j<64] @8192, fc1L[j<64] @12288
//   phase 2b: fc1H[j>=64] @8192, fc1L[j>=64] @12288
__global__ __launch_bounds__(256) void pw_head_mfma(
    const float* __restrict__ x1, const float* __restrict__ v,
    const u16* __restrict__ wcH, const u16* __restrict__ wcL,
    const float* __restrict__ cb,
    const u16* __restrict__ whH, const u16* __restrict__ whL,
    const float* __restrict__ fc1b, const float* __restrict__ fc2w,
    const float* __restrict__ fc2b, float* __restrict__ out)
{
  __shared__ alignas(16) u16 pool[16384];   // 32 KB
  __shared__ float cbl[64], f1b[128], f2w[128];
  u16 (*aH)[64] = (u16(*)[64])(pool);
  u16 (*aL)[64] = (u16(*)[64])(pool + 4096);
  int b  = blockIdx.x >> 7;
  int s0 = (blockIdx.x & 127) << 6;
  int t  = threadIdx.x;

  {  // phase-1 weights: cw into pool[8192..16383]
    const v8s* srcH = (const v8s*)wcH;
    const v8s* srcL = (const v8s*)wcL;
    v8s* dstH = (v8s*)(pool + 8192);
    v8s* dstL = (v8s*)(pool + 12288);
    #pragma unroll
    for (int r = 0; r < 2; ++r) {
      dstH[t + 256 * r] = srcH[t + 256 * r];
      dstL[t + 256 * r] = srcL[t + 256 * r];
    }
  }
  if (t < 64) cbl[t] = cb[t];
  if (t < 128) { f1b[t] = fc1b[t]; f2w[t] = fc2w[t]; }

  #pragma unroll
  for (int r = 0; r < 4; ++r) {
    int idx = t + 256 * r;
    int ch = idx >> 4, p4 = (idx & 15) << 2;
    float4 xv = *(const float4*)&v[((size_t)(b * 64 + ch)) * S_LEN + s0 + p4];
    u16 h0 = bf16_rn(xv.x); aH[p4+0][ch ^ (((p4+0)&7)<<3)] = h0; aL[p4+0][ch ^ (((p4+0)&7)<<3)] = bf16_rn(xv.x - bf16_to_f(h0));
    u16 h1 = bf16_rn(xv.y); aH[p4+1][ch ^ (((p4+1)&7)<<3)] = h1; aL[p4+1][ch ^ (((p4+1)&7)<<3)] = bf16_rn(xv.y - bf16_to_f(h1));
    u16 h2 = bf16_rn(xv.z); aH[p4+2][ch ^ (((p4+2)&7)<<3)] = h2; aL[p4+2][ch ^ (((p4+2)&7)<<3)] = bf16_rn(xv.z - bf16_to_f(h2));
    u16 h3 = bf16_rn(xv.w); aH[p4+3][ch ^ (((p4+3)&7)<<3)] = h3; aL[p4+3][ch ^ (((p4+3)&7)<<3)] = bf16_rn(xv.w - bf16_to_f(h3));
  }
  __syncthreads();

  int l = t & 63, wv_ = t >> 6;
  int pi = l & 15, kg = l >> 4;
  int pos = wv_ * 16 + pi;
  int swz = (pi & 7) << 3;

  // ---- pw MFMA (cw mix, K=64)
  v4f acc[4];
  #pragma unroll
  for (int i = 0; i < 4; ++i) acc[i] = v4f{0.f, 0.f, 0.f, 0.f};
  #pragma unroll
  for (int kt = 0; kt < 2; ++kt) {
    int ka = (kg * 8 + kt * 32) ^ swz;
    v8s ah = *(const v8s*)&aH[pos][ka];
    v8s al = *(const v8s*)&aL[pos][ka];
    #pragma unroll
    for (int ct = 0; ct < 4; ++ct) {
      int o = ct * 16 + pi;
      v8s bh = *(const v8s*)&pool[8192  + o * 64 + ka];
      v8s bl = *(const v8s*)&pool[12288 + o * 64 + ka];
      acc[ct] = __builtin_amdgcn_mfma_f32_16x16x32_bf16(ah, bh, acc[ct], 0, 0, 0);
      acc[ct] = __builtin_amdgcn_mfma_f32_16x16x32_bf16(ah, bl, acc[ct], 0, 0, 0);
      acc[ct] = __builtin_amdgcn_mfma_f32_16x16x32_bf16(al, bh, acc[ct], 0, 0, 0);
    }
  }
  __syncthreads();   // all reads of aH/aL and cw region complete

  // ---- restage fc1 half 1 (j<64) into weight window; y-writeback into aH/aL
  {
    const v8s* srcH = (const v8s*)whH;
    const v8s* srcL = (const v8s*)whL;
    v8s* dstH = (v8s*)(pool + 8192);
    v8s* dstL = (v8s*)(pool + 12288);
    #pragma unroll
    for (int r = 0; r < 2; ++r) {
      dstH[t + 256 * r] = srcH[t + 256 * r];
      dstL[t + 256 * r] = srcL[t + 256 * r];
    }
  }
  #pragma unroll
  for (int ct = 0; ct < 4; ++ct) {
    int o = ct * 16 + pi;
    size_t base = ((size_t)(b * 64 + o)) * S_LEN + s0 + wv_ * 16 + kg * 4;
    float4 x4 = *(const float4*)&x1[base];
    float cbv = cbl[o];
    float y[4] = { acc[ct][0] + x4.x + cbv, acc[ct][1] + x4.y + cbv,
                   acc[ct][2] + x4.z + cbv, acc[ct][3] + x4.w + cbv };
    #pragma unroll
    for (int d = 0; d < 4; ++d) {
      int p = wv_ * 16 + kg * 4 + d;
      int cs = o ^ ((p & 7) << 3);
      u16 h = bf16_rn(y[d]);
      aH[p][cs] = h;
      aL[p][cs] = bf16_rn(y[d] - bf16_to_f(h));
    }
  }
  __syncthreads();

  // ---- head MFMA half 1 (j = 0..63 -> ct 0..3)
  v4f hacc[8];
  #pragma unroll
  for (int i = 0; i < 8; ++i) hacc[i] = v4f{0.f, 0.f, 0.f, 0.f};
  #pragma unroll
  for (int kt = 0; kt < 2; ++kt) {
    int ka = (kg * 8 + kt * 32) ^ swz;
    v8s ah = *(const v8s*)&aH[pos][ka];
    v8s al = *(const v8s*)&aL[pos][ka];
    #pragma unroll
    for (int ct = 0; ct < 4; ++ct) {
      int j = ct * 16 + pi;   // < 64
      v8s bh = *(const v8s*)&pool[8192  + j * 64 + ka];
      v8s bl = *(const v8s*)&pool[12288 + j * 64 + ka];
      hacc[ct] = __builtin_amdgcn_mfma_f32_16x16x32_bf16(ah, bh, hacc[ct], 0, 0, 0);
      hacc[ct] = __builtin_amdgcn_mfma_f32_16x16x32_bf16(ah, bl, hacc[ct], 0, 0, 0);
      hacc[ct] = __builtin_amdgcn_mfma_f32_16x16x32_bf16(al, bh, hacc[ct], 0, 0, 0);
    }
  }
  __syncthreads();   // weight-window reads complete

  // ---- restage fc1 half 2 (j>=64)
  {
    const v8s* srcH = (const v8s*)(whH + 4096);
    const v8s* srcL = (const v8s*)(whL + 4096);
    v8s* dstH = (v8s*)(pool + 8192);
    v8s* dstL = (v8s*)(pool + 12288);
    #pragma unroll
    for (int r = 0; r < 2; ++r) {
      dstH[t + 256 * r] = srcH[t + 256 * r];
      dstL[t + 256 * r] = srcL[t + 256 * r];
    }
  }
  __syncthreads();

  // ---- head MFMA half 2 (j = 64..127 -> ct 4..7)
  #pragma unroll
  for (int kt = 0; kt < 2; ++kt) {
    int ka = (kg * 8 + kt * 32) ^ swz;
    v8s ah = *(const v8s*)&aH[pos][ka];
    v8s al = *(const v8s*)&aL[pos][ka];
    #pragma unroll
    for (int ct = 4; ct < 8; ++ct) {
      int jr = (ct - 4) * 16 + pi;   // row within half
      v8s bh = *(const v8s*)&pool[8192  + jr * 64 + ka];
      v8s bl = *(const v8s*)&pool[12288 + jr * 64 + ka];
      hacc[ct] = __builtin_amdgcn_mfma_f32_16x16x32_bf16(ah, bh, hacc[ct], 0, 0, 0);
      hacc[ct] = __builtin_amdgcn_mfma_f32_16x16x32_bf16(ah, bl, hacc[ct], 0, 0, 0);
      hacc[ct] = __builtin_amdgcn_mfma_f32_16x16x32_bf16(al, bh, hacc[ct], 0, 0, 0);
    }
  }

  float part[4] = {0.f, 0.f, 0.f, 0.f};
  #pragma unroll
  for (int ct = 0; ct < 8; ++ct) {
    int j = ct * 16 + pi;
    float bias = f1b[j], f2 = f2w[j];
    #pragma unroll
    for (int r = 0; r < 4; ++r) {
      float d = hacc[ct][r] + bias;
      part[r] += f2 * gelu_f(d);
    }
  }
  #pragma unroll
  for (int r = 0; r < 4; ++r) {
    part[r] += __shfl_xor(part[r], 1, 16);
    part[r] += __shfl_xor(part[r], 2, 16);
    part[r] += __shfl_xor(part[r], 4, 16);
    part[r] += __shfl_xor(part[r], 8, 16);
  }
  if (pi == 0) {
    float b2 = fc2b[0];
    float4 o4 = make_float4(part[0] + b2, part[1] + b2, part[2] + b2, part[3] + b2);
    *(float4*)&out[(size_t)b * S_LEN + s0 + wv_ * 16 + kg * 4] = o4;
  }
}

// ----------------------------------------------------------------
extern "C" void kernel_launch(void* const* d_in, const int* in_sizes, int n_in,
                              void* d_out, int out_size, void* d_ws, size_t ws_size,
                              hipStream_t stream) {
  const float* x    = (const float*)d_in[0];
  const float* fc0w = (const float*)d_in[1];
  const float* fc0b = (const float*)d_in[2];
  const float* w1   = (const float*)d_in[3];
  const float* w2   = (const float*)d_in[4];
  const float* cw   = (const float*)d_in[5];
  const float* cb   = (const float*)d_in[6];
  const float* fc1w = (const float*)d_in[7];
  const float* fc1b = (const float*)d_in[8];
  const float* fc2w = (const float*)d_in[9];
  const float* fc2b = (const float*)d_in[10];
  float* out = (float*)d_out;

  float* ws     = (float*)d_ws;
  float* v      = ws;
  float* x1     = v      + (size_t)BC * S_LEN;
  float* highs  = x1     + (size_t)BC * S_LEN;
  float* yl_raw = highs  + (size_t)BC * HTOT;
  float* lo_f   = yl_raw + (size_t)BC * MODES;
  float* lo_i   = lo_f   + (size_t)BC * LO_STR;
  u16*   whH    = (u16*)(lo_i + (size_t)BC * LO_STR);
  u16*   whL    = whH + 8192;
  u16*   wcH    = whL + 8192;
  u16*   wcL    = wcH + 16384;
  size_t needed = (size_t)((char*)(wcL + 16384) - (char*)ws);
  if (ws_size < needed) return;

  prep_split<<<96, 256, 0, stream>>>(fc1w, cw, whH, whL, wcH, wcL);
  fc0_kernel<<<16384, 256, 0, stream>>>(x, fc0w, fc0b, v);

  for (int i = 0; i < 4; ++i) {
    const float* w1l = w1 + (size_t)i * 64 * 64 * MODES;
    const float* w2l = w2 + (size_t)i * 64 * 64 * MODES;
    dwt_big<<<BC * 4, 256, 0, stream>>>(v, highs, lo_f);
    dwt_small<<<BC / 4, 256, 0, stream>>>(lo_f, highs, yl_raw);
    idwt_small<<<BC / 4, 256, 0, stream>>>(yl_raw, highs, w1l, w2l, lo_i);
    idwt_big<<<BC * 4, 256, 0, stream>>>(lo_i, highs, x1);
    if (i < 3) {
      pw_mfma<<<4096, 256, 0, stream>>>(x1, v, wcH + i * 4096, wcL + i * 4096, cb + i * 64);
    } else {
      pw_head_mfma<<<4096, 256, 0, stream>>>(x1, v, wcH + i * 4096, wcL + i * 4096, cb + i * 64,
                                             whH, whL, fc1b, fc2w, fc2b, out);
    }
  }
}